// Round 15
// baseline (158.107 us; speedup 1.0000x reference)
//
#include <hip/hip_runtime.h>
#include <stdint.h>

#define BATCH 8
#define NN 262144
#define K_PRE 6000
#define NPROP 1000
#define NMS_THR 0.7f
#define CAND_CAP 8192
#define CANDC_CAP 16384
#define PREFIX 2048
#define NB1 16384
#define NB2 4096
#define RBINS 4096
#define TSAMP 688      // sample-count target: ~11000 actual admitted (x16 scale)
#define NTILT 528      // lower-triangle tiles: 32*33/2

// meta u32 indices
#define MT_T2 0        // [0..7]   final threshold
#define MT_KEPT 16     // [16..23] kept count
#define MT_T1 24       // [24..31] coarse bucket
#define MT_CUM 32      // [32..39] cum count above coarse bucket
#define MT_TG 40       // [40..47] speculative stash threshold
#define MT_VALID 48    // [48..55] stash validity flag
#define MT_OVF 56      // [56..63] local-stash overflow flag
#define MT_CNT(b)   (64 + 32*(b))       // exact candidate count
#define MT_CNTC(b)  (64 + 32*(b) + 16)  // pass-1 stash count
#define MT_CNTC2(b) (64 + 32*(b) + 24)  // fallback stash count

// workspace layout (bytes)
#define HIST1_OFF 0                                   // BATCH*NB1*4 = 524288
#define HIST2_OFF (HIST1_OFF + BATCH*NB1*4)           // + BATCH*NB2*4 = 131072
#define META_OFF  (HIST2_OFF + BATCH*NB2*4)           // 2048 B
#define CAND_OFF  (META_OFF + 2048)
#define BOXES_OFF (CAND_OFF + BATCH*CAND_CAP*8)       // BATCH*K_PRE*16
#define MASK_OFF  (BOXES_OFF + BATCH*K_PRE*16)        // BATCH*PREFIX*64*4 = 4 MB
#define KIDX_OFF  (MASK_OFF + (size_t)BATCH*PREFIX*64*4)
#define CANDC_OFF (KIDX_OFF + BATCH*NPROP*4)          // BATCH*CANDC_CAP*8 = 1 MB
#define WS_NEED   (CANDC_OFF + (size_t)BATCH*CANDC_CAP*8)

// region reuse:
//  - sinfo (u64[BATCH*PREFIX] = 128KB) -> HIST1 region (dead after k_thresh)
//  - cbm (u32[BATCH*64] = 2KB)         -> HIST2 region (dead after k_thresh2f)
//  - ranks (u32[BATCH*CAND_CAP])       -> CANDC region (dead after k_thresh2f)

__device__ __forceinline__ uint32_t fkey(float f) {
    uint32_t b = __float_as_uint(f);
    return b ^ (uint32_t)(((int32_t)b >> 31) | 0x80000000u);
}

// Per-batch: zero hists/counters + sample 16384 scores (16 contiguous chunks)
// to pick speculative stash threshold Tg (targets ~11K admitted; any error is
// caught by the validity check -> exact fallback).
__global__ __launch_bounds__(256) void k_sample(const float4* __restrict__ probs4,
        uint32_t* meta, uint32_t* __restrict__ hist1, uint32_t* __restrict__ hist2) {
    __shared__ uint32_t h[NB1];
    __shared__ uint32_t part[256];
    const int b = blockIdx.x;
    uint32_t* gh1 = hist1 + (size_t)b * NB1;
    uint32_t* gh2 = hist2 + (size_t)b * NB2;
    for (int i = threadIdx.x; i < NB1; i += 256) { gh1[i] = 0; h[i] = 0; }
    for (int i = threadIdx.x; i < NB2; i += 256) gh2[i] = 0;
    if (threadIdx.x == 0) {
        meta[MT_CNTC(b)] = 0;
        meta[MT_CNTC2(b)] = 0;
        meta[MT_OVF + b] = 0;
    }
    __syncthreads();
    const float4* p = probs4 + (size_t)b * (NN / 2);
    for (int c = 0; c < 16; ++c) {
        const float4* pc = p + c * (NN / 2 / 16);
        for (int i = threadIdx.x; i < 512; i += 256) {
            const float4 v = pc[i];
            atomicAdd(&h[fkey(v.y) >> 18], 1u);
            atomicAdd(&h[fkey(v.w) >> 18], 1u);
        }
    }
    __syncthreads();
    const int t = threadIdx.x;
    uint32_t s = 0;
    const int hi = NB1 - 64 * t;
    for (int i = hi - 64; i < hi; ++i) s += h[i];
    part[t] = s;
    __syncthreads();
    if (t == 0) {
        uint32_t cum = 0;
        int strip = 0;
        for (; strip < 256; ++strip) {
            if (cum + part[strip] >= (uint32_t)TSAMP) break;
            cum += part[strip];
        }
        int B = 0;
        if (strip < 256) {
            const int top = NB1 - 64 * strip;
            int i = top - 1;
            for (; i >= top - 64; --i) {
                if (cum + h[i] >= (uint32_t)TSAMP) break;
                cum += h[i];
            }
            if (i < top - 64) i = top - 64;
            B = i;
        }
        meta[MT_TG + b] = (uint32_t)B << 18;
    }
}

// THE single full 16.8MB pass: 16K-bin histogram + speculative stash (u >= Tg).
__global__ __launch_bounds__(256) void k_histc(const float4* __restrict__ probs4,
        const uint32_t* __restrict__ meta_r, uint32_t* meta_w,
        uint32_t* __restrict__ hist, uint64_t* __restrict__ cand_c) {
    __shared__ uint32_t h[NB1];        // 64 KB
    __shared__ uint64_t stash[2048];   // 16 KB
    __shared__ uint32_t lcnt, lbase;
    for (int i = threadIdx.x; i < NB1; i += 256) h[i] = 0;
    if (threadIdx.x == 0) lcnt = 0;
    __syncthreads();
    const int b = blockIdx.x >> 6;
    const int s = blockIdx.x & 63;
    const uint32_t Tg = meta_r[MT_TG + b];
    const float4* p = probs4 + (size_t)b * (NN / 2) + (size_t)s * 2048;
    const uint32_t base_n = (uint32_t)s * 4096;
    for (int i = threadIdx.x; i < 2048; i += 256) {
        const float4 v = p[i];
        const uint32_t u1 = fkey(v.y), u2 = fkey(v.w);
        atomicAdd(&h[u1 >> 18], 1u);
        atomicAdd(&h[u2 >> 18], 1u);
        if (u1 >= Tg) {
            const uint32_t pos = atomicAdd(&lcnt, 1u);
            if (pos < 2048) stash[pos] = ((uint64_t)u1 << 32) | (uint32_t)(~(base_n + 2u * (uint32_t)i));
        }
        if (u2 >= Tg) {
            const uint32_t pos = atomicAdd(&lcnt, 1u);
            if (pos < 2048) stash[pos] = ((uint64_t)u2 << 32) | (uint32_t)(~(base_n + 2u * (uint32_t)i + 1u));
        }
    }
    __syncthreads();
    uint32_t* gh = hist + (size_t)b * NB1;
    for (int i = threadIdx.x; i < NB1; i += 256)
        if (h[i]) atomicAdd(&gh[i], h[i]);
    if (threadIdx.x == 0) {
        if (lcnt > 2048) atomicOr(&meta_w[MT_OVF + b], 1u);
        lbase = atomicAdd(&meta_w[MT_CNTC(b)], min(lcnt, 2048u));
    }
    __syncthreads();
    uint64_t* cc = cand_c + (size_t)b * CANDC_CAP;
    const uint32_t n_loc = min(lcnt, 2048u), base = lbase;
    for (uint32_t i = threadIdx.x; i < n_loc; i += 256) {
        const uint32_t pos = base + i;
        if (pos < CANDC_CAP) cc[pos] = stash[i];
    }
}

__global__ __launch_bounds__(256) void k_thresh(const uint32_t* __restrict__ hist,
                                                uint32_t* meta) {
    const int b = blockIdx.x;
    const uint32_t* gh = hist + (size_t)b * NB1;
    __shared__ uint32_t part[256];
    const int t = threadIdx.x;
    uint32_t s = 0;
    const int hi = NB1 - 64 * t;
    for (int i = hi - 64; i < hi; ++i) s += gh[i];
    part[t] = s;
    __syncthreads();
    if (t == 0) {
        uint32_t cum = 0;
        int strip = 0;
        for (; strip < 256; ++strip) {
            if (cum + part[strip] >= (uint32_t)K_PRE) break;
            cum += part[strip];
        }
        int t1 = 0;
        if (strip < 256) {
            const int top = NB1 - 64 * strip;
            int i = top - 1;
            for (; i >= top - 64; --i) {
                const uint32_t c = gh[i];
                if (cum + c >= (uint32_t)K_PRE) break;
                cum += c;
            }
            if (i < top - 64) i = top - 64;
            t1 = i;
        }
        meta[MT_T1 + b] = (uint32_t)t1;
        meta[MT_CUM + b] = cum;
        const uint32_t Tg = meta[MT_TG + b];
        const uint32_t cc = meta[MT_CNTC(b)];
        const uint32_t ovf = meta[MT_OVF + b];
        meta[MT_VALID + b] =
            ((Tg >> 18) <= (uint32_t)t1 && cc <= (uint32_t)CANDC_CAP && !ovf) ? 1u : 0u;
    }
}

// Fine histogram of bucket t1. Valid stash: built from 130KB stash (1 block/
// batch). Invalid: full probs fallback pass that also re-stashes (cntc2).
__global__ __launch_bounds__(256) void k_hist2s(const float4* __restrict__ probs4,
        uint32_t* meta, uint32_t* __restrict__ hist2, uint64_t* __restrict__ cand_c) {
    __shared__ uint32_t shmem[NB2];    // 16 KB (aliased as stash in fallback)
    const int b = blockIdx.x >> 8;
    const int s = blockIdx.x & 255;
    const uint32_t valid = meta[MT_VALID + b];
    const uint32_t t1 = meta[MT_T1 + b];
    uint32_t* gh = hist2 + (size_t)b * NB2;
    if (valid) {
        if (s != 0) return;
        for (int i = threadIdx.x; i < NB2; i += 256) shmem[i] = 0;
        __syncthreads();
        const uint64_t* cc = cand_c + (size_t)b * CANDC_CAP;
        const uint32_t mc = meta[MT_CNTC(b)];
        for (uint32_t i = threadIdx.x; i < mc; i += 256) {
            const uint32_t khi = (uint32_t)(cc[i] >> 32);
            if ((khi >> 18) == t1) atomicAdd(&shmem[(khi >> 6) & 0xFFFu], 1u);
        }
        __syncthreads();
        for (int i = threadIdx.x; i < NB2; i += 256)
            if (shmem[i]) gh[i] = shmem[i];   // hist2 pre-zeroed; single writer
    } else {
        uint64_t* stash = (uint64_t*)shmem;   // 1024 u64 = 8 KB
        __shared__ uint32_t lcnt, lbase;
        const uint32_t Tc = t1 << 18;
        if (threadIdx.x == 0) lcnt = 0;
        __syncthreads();
        const float4* p = probs4 + (size_t)b * (NN / 2) + (size_t)s * 512;
        const uint32_t base_n = (uint32_t)s * 1024;
        for (int i = threadIdx.x; i < 512; i += 256) {
            const float4 v = p[i];
            const uint32_t u1 = fkey(v.y), u2 = fkey(v.w);
            if ((u1 >> 18) == t1) atomicAdd(&gh[(u1 >> 6) & 0xFFFu], 1u);
            if ((u2 >> 18) == t1) atomicAdd(&gh[(u2 >> 6) & 0xFFFu], 1u);
            if (u1 >= Tc) {
                const uint32_t pos = atomicAdd(&lcnt, 1u);
                if (pos < 1024) stash[pos] = ((uint64_t)u1 << 32) | (uint32_t)(~(base_n + 2u * (uint32_t)i));
            }
            if (u2 >= Tc) {
                const uint32_t pos = atomicAdd(&lcnt, 1u);
                if (pos < 1024) stash[pos] = ((uint64_t)u2 << 32) | (uint32_t)(~(base_n + 2u * (uint32_t)i + 1u));
            }
        }
        __syncthreads();
        if (threadIdx.x == 0) lbase = atomicAdd(&meta[MT_CNTC2(b)], min(lcnt, 1024u));
        __syncthreads();
        uint64_t* cc = cand_c + (size_t)b * CANDC_CAP;
        const uint32_t n_loc = min(lcnt, 1024u), base = lbase;
        for (uint32_t i = threadIdx.x; i < n_loc; i += 256) {
            const uint32_t pos = base + i;
            if (pos < CANDC_CAP) cc[pos] = stash[i];
        }
    }
}

// Fused: fine-threshold T2 selection + stash filter -> exact candidate set.
__global__ __launch_bounds__(256) void k_thresh2f(const uint32_t* __restrict__ hist2,
        uint32_t* meta, const uint64_t* __restrict__ cand_c, uint64_t* __restrict__ cand) {
    const int b = blockIdx.x;
    const uint32_t* gh = hist2 + (size_t)b * NB2;
    __shared__ uint32_t part[256];
    __shared__ uint32_t sT2, scnt;
    const int t = threadIdx.x;
    uint32_t s = 0;
    const int hi = NB2 - 16 * t;
    for (int i = hi - 16; i < hi; ++i) s += gh[i];
    part[t] = s;
    __syncthreads();
    if (t == 0) {
        const uint32_t t1 = meta[MT_T1 + b];
        uint32_t cum = meta[MT_CUM + b];
        int strip = 0;
        for (; strip < 256; ++strip) {
            if (cum + part[strip] >= (uint32_t)K_PRE) break;
            cum += part[strip];
        }
        int sub = 0;
        if (strip < 256) {
            const int top = NB2 - 16 * strip;
            int i = top - 1;
            for (; i >= top - 16; --i) {
                const uint32_t c = gh[i];
                if (cum + c >= (uint32_t)K_PRE) break;
                cum += c;
            }
            if (i < top - 16) i = top - 16;
            sub = i;
        }
        sT2 = (t1 << 18) | ((uint32_t)sub << 6);
        meta[MT_T2 + b] = sT2;
        meta[MT_KEPT + b] = 0;
        scnt = 0;
    }
    __syncthreads();
    const uint32_t T = sT2;
    const uint32_t valid = meta[MT_VALID + b];
    const uint32_t mc = min(valid ? meta[MT_CNTC(b)] : meta[MT_CNTC2(b)], (uint32_t)CANDC_CAP);
    const uint64_t* cc = cand_c + (size_t)b * CANDC_CAP;
    uint64_t* cb = cand + (size_t)b * CAND_CAP;
    for (uint32_t i = (uint32_t)t; i < mc; i += 256) {
        const uint64_t k = cc[i];
        if ((uint32_t)(k >> 32) >= T) {
            const uint32_t pos = atomicAdd(&scnt, 1u);
            if (pos < CAND_CAP) cb[pos] = k;
        }
    }
    __syncthreads();
    if (t == 0) meta[MT_CNT(b)] = scnt;
}

// Rank via monotone binning + suffix scan + within-bin exact compare.
__global__ __launch_bounds__(1024) void k_rankonly(const uint64_t* __restrict__ cand,
        const uint32_t* __restrict__ meta, uint32_t* __restrict__ ranks) {
    __shared__ uint64_t skey[CAND_CAP];
    __shared__ uint16_t sbin[CAND_CAP];
    __shared__ uint32_t cnt[RBINS];
    __shared__ uint32_t S[RBINS];
    __shared__ uint16_t order[CAND_CAP];
    __shared__ uint32_t sc[1024];
    const int b = blockIdx.x;
    const int t = threadIdx.x;
    const uint32_t m = min(meta[MT_CNT(b)], (uint32_t)CAND_CAP);
    const uint32_t T2 = meta[MT_T2 + b];
    const uint32_t R = 0xBF800000u - T2;
    const int w = 32 - __clz(R | 1);
    const int sh = (w > 12) ? (w - 12) : 0;
    for (int i = t; i < RBINS; i += 1024) cnt[i] = 0;
    __syncthreads();
    const uint64_t* cb = cand + (size_t)b * CAND_CAP;
    for (uint32_t i = t; i < m; i += 1024) {
        const uint64_t k = cb[i];
        skey[i] = k;
        uint32_t bin = (((uint32_t)(k >> 32)) - T2) >> sh;
        if (bin >= RBINS) bin = RBINS - 1;
        sbin[i] = (uint16_t)bin;
        atomicAdd(&cnt[bin], 1u);
    }
    __syncthreads();
    const uint32_t c1 = cnt[4 * t + 1], c2 = cnt[4 * t + 2], c3 = cnt[4 * t + 3];
    sc[t] = cnt[4 * t] + c1 + c2 + c3;
    __syncthreads();
    for (int d = 1; d < 1024; d <<= 1) {
        const uint32_t v = (t + d < 1024) ? sc[t + d] : 0;
        __syncthreads();
        sc[t] += v;
        __syncthreads();
    }
    const uint32_t Spart = (t + 1 < 1024) ? sc[t + 1] : 0;
    S[4 * t + 3] = Spart;
    S[4 * t + 2] = Spart + c3;
    S[4 * t + 1] = Spart + c3 + c2;
    S[4 * t + 0] = Spart + c3 + c2 + c1;
    __syncthreads();
    for (uint32_t i = t; i < m; i += 1024) {
        const uint32_t bin = sbin[i];
        const uint32_t intra = atomicSub(&cnt[bin], 1u) - 1u;
        order[S[bin] + intra] = (uint16_t)i;
    }
    __syncthreads();
    uint32_t* rb = ranks + (size_t)b * CAND_CAP;
    for (uint32_t i = t; i < m; i += 1024) {
        const uint32_t bin = sbin[i];
        const uint64_t ki = skey[i];
        const uint32_t start = S[bin];
        const uint32_t end = (bin > 0) ? S[bin - 1] : m;
        uint32_t rank = start;
        for (uint32_t s2 = start; s2 < end; ++s2)
            if (skey[order[s2]] > ki) ++rank;
        rb[i] = rank;
    }
}

// Decode gather with full parallelism (256 blocks).
__global__ __launch_bounds__(256) void k_decode(const uint64_t* __restrict__ cand,
        const uint32_t* __restrict__ meta, const uint32_t* __restrict__ ranks,
        const float4* __restrict__ bbox, const float4* __restrict__ anch,
        float4* __restrict__ boxes) {
    const int b = blockIdx.x >> 5;
    const int i = ((blockIdx.x & 31) << 8) + threadIdx.x;
    const uint32_t m = min(meta[MT_CNT(b)], (uint32_t)CAND_CAP);
    if ((uint32_t)i >= m) return;
    const uint32_t rank = ranks[(size_t)b * CAND_CAP + i];
    if (rank >= (uint32_t)K_PRE) return;
    const uint64_t ki = cand[(size_t)b * CAND_CAP + i];
    const uint32_t n = ~((uint32_t)ki);
    const float4 a = anch[(size_t)b * NN + n];
    const float4 d = bbox[(size_t)b * NN + n];
    float h = a.z - a.x, w = a.w - a.y;
    const float cy0 = a.x + 0.5f * h + d.x * 0.1f * h;
    const float cx0 = a.y + 0.5f * w + d.y * 0.1f * w;
    h = h * expf(d.z * 0.2f);
    w = w * expf(d.w * 0.2f);
    float4 o;
    o.x = fminf(fmaxf(cy0 - 0.5f * h, 0.0f), 1.0f);
    o.y = fminf(fmaxf(cx0 - 0.5f * w, 0.0f), 1.0f);
    o.z = fminf(fmaxf(cy0 + 0.5f * h, 0.0f), 1.0f);
    o.w = fminf(fmaxf(cx0 + 0.5f * w, 0.0f), 1.0f);
    boxes[(size_t)b * K_PRE + rank] = o;
}

// IoU bit-matrix, LOWER TRIANGLE tiles only (tj <= ti) — consumers mask
// everything above the diagonal, so upper tiles are never read as data.
__global__ __launch_bounds__(256) void k_matrix(const float4* __restrict__ boxes,
                                                uint32_t* __restrict__ mask) {
    const int b = blockIdx.x / NTILT;
    const int idx = blockIdx.x - b * NTILT;
    int ti = (int)((sqrtf(8.0f * (float)idx + 1.0f) - 1.0f) * 0.5f);
    while ((ti + 1) * (ti + 2) / 2 <= idx) ++ti;
    while (ti * (ti + 1) / 2 > idx) --ti;
    const int tj = idx - ti * (ti + 1) / 2;
    __shared__ float4 rb[64], cb[64];
    __shared__ uint32_t wbits[128];
    const float4* bx = boxes + (size_t)b * K_PRE;
    const int t = threadIdx.x;
    if (t < 64) rb[t] = bx[ti * 64 + t];
    else if (t < 128) cb[t - 64] = bx[tj * 64 + (t - 64)];
    if (t < 128) wbits[t] = 0;
    __syncthreads();
    const int r = t >> 2;
    const int cq = t & 3;
    const float4 a = rb[r];
    const float areaA = (a.z - a.x) * (a.w - a.y);
    uint32_t bits = 0;
#pragma unroll
    for (int jj = 0; jj < 16; ++jj) {
        const float4 cc = cb[cq * 16 + jj];
        const float yy1 = fmaxf(a.x, cc.x), xx1 = fmaxf(a.y, cc.y);
        const float yy2 = fminf(a.z, cc.z), xx2 = fminf(a.w, cc.w);
        const float inter = fmaxf(yy2 - yy1, 0.0f) * fmaxf(xx2 - xx1, 0.0f);
        const float areaC = (cc.z - cc.x) * (cc.w - cc.y);
        const float uni = fmaxf(areaA + areaC - inter, 1e-8f);
        if (inter / uni > NMS_THR) bits |= (1u << jj);
    }
    atomicOr(&wbits[r * 2 + (cq >> 1)], bits << ((cq & 1) * 16));
    __syncthreads();
    if (t < 128) {
        const int rr = t >> 1, ww = t & 1;
        mask[((size_t)b * PREFIX + ti * 64 + rr) * 64 + tj * 2 + ww] = wbits[rr * 2 + ww];
    }
}

// Conflict extraction (lower triangle only; words > iw masked).
__global__ __launch_bounds__(256) void k_conflict(const uint32_t* __restrict__ mask,
        uint64_t* __restrict__ sinfo, uint32_t* __restrict__ cbm) {
    const int b = blockIdx.x >> 3;
    const int s = blockIdx.x & 7;
    const int i = (s << 8) + threadIdx.x;
    const uint4* row4 = (const uint4*)(mask + ((size_t)b * PREFIX + i) * 64);
    const int iw = i >> 5;
    const uint32_t tailmask = ((uint32_t)1 << (i & 31)) - 1u;
    uint32_t cnt = 0;
    uint64_t packed = 0;
    for (int c = 0; c <= (iw >> 2); ++c) {
        const uint4 q = row4[c];
        uint32_t ws[4] = {q.x, q.y, q.z, q.w};
#pragma unroll
        for (int k = 0; k < 4; ++k) {
            const int w = c * 4 + k;
            uint32_t bits = ws[k];
            if (w > iw) bits = 0;
            else if (w == iw) bits &= tailmask;
            while (bits) {
                const int bp = __ffs(bits) - 1;
                bits &= bits - 1;
                if (cnt < 5) packed |= (uint64_t)(uint32_t)(w * 32 + bp) << (12 * cnt);
                ++cnt;
            }
        }
    }
    packed |= (uint64_t)(cnt <= 5 ? cnt : 6) << 60;
    sinfo[(size_t)b * PREFIX + i] = packed;
    const unsigned long long bm = __ballot(cnt != 0);
    const int wv = threadIdx.x >> 6;
    const int lid = threadIdx.x & 63;
    if (lid == 0) cbm[(size_t)b * 64 + (s << 3) + wv * 2] = (uint32_t)bm;
    else if (lid == 1) cbm[(size_t)b * 64 + (s << 3) + wv * 2 + 1] = (uint32_t)(bm >> 32);
}

// Greedy resolution via conflicted-row sparse resolve.
__global__ __launch_bounds__(64) void k_greedy(const uint32_t* __restrict__ mask,
        const uint64_t* __restrict__ sinfo, const uint32_t* __restrict__ cbm,
        uint32_t* meta, uint32_t* __restrict__ kept_idx) {
    __shared__ uint32_t conf_rows[PREFIX];
    __shared__ uint32_t ncf_s;
    const int b = blockIdx.x;
    const int lane = threadIdx.x;
    const uint32_t cw = cbm[(size_t)b * 64 + lane];
    uint32_t taken = 0xFFFFFFFFu;

    const uint32_t pc = (uint32_t)__popc(cw);
    uint32_t pref = pc;
    for (int d = 1; d < 64; d <<= 1) {
        const uint32_t v = __shfl_up(pref, d);
        if (lane >= d) pref += v;
    }
    const uint32_t ncf = __shfl(pref, 63);
    uint32_t idx = pref - pc;
    uint32_t tm = cw;
    while (tm) {
        const int q = __ffs(tm) - 1;
        tm &= tm - 1;
        conf_rows[idx] = (uint32_t)(lane * 32 + q);
        ++idx;
    }
    if (lane == 0) ncf_s = ncf;
    __syncthreads();

    uint32_t r_i[4], r_lo[4], r_hi[4];
#pragma unroll
    for (int r = 0; r < 4; ++r) {
        const uint32_t k = (uint32_t)(r * 64 + lane);
        const uint32_t ri = (k < ncf) ? conf_rows[k] : 0;
        const uint64_t nf = (k < ncf) ? sinfo[(size_t)b * PREFIX + ri] : 0ull;
        r_i[r] = ri;
        r_lo[r] = (uint32_t)nf;
        r_hi[r] = (uint32_t)(nf >> 32);
    }

    const uint32_t* mbase = mask + (size_t)b * PREFIX * 64;

#pragma unroll
    for (int seg = 0; seg < 4; ++seg) {
        const uint32_t segbase = (uint32_t)(seg * 64);
        if (segbase < ncf) {
            const uint32_t segcnt = min(64u, ncf - segbase);
            for (uint32_t k2 = 0; k2 < segcnt; ++k2) {
                const uint32_t i  = __builtin_amdgcn_readlane(r_i[seg], (int)k2);
                const uint32_t lo = __builtin_amdgcn_readlane(r_lo[seg], (int)k2);
                const uint32_t hi = __builtin_amdgcn_readlane(r_hi[seg], (int)k2);
                const uint32_t cnt = hi >> 28;
                bool dropped = false;
                if (cnt == 6) {
                    const uint32_t* row = mbase + (size_t)i * 64;
                    const int iw = i >> 5;
                    for (int w = 0; w <= iw; ++w) {
                        uint32_t bits = row[w];
                        if (w == iw) bits &= (((uint32_t)1 << (i & 31)) - 1u);
                        const uint32_t tk = __builtin_amdgcn_readlane(taken, w);
                        if (bits & tk) { dropped = true; break; }
                    }
                } else {
                    uint64_t p = ((uint64_t)hi << 32) | lo;
                    for (uint32_t c = 0; c < cnt; ++c) {
                        const uint32_t j = (uint32_t)(p & 0xFFFu);
                        p >>= 12;
                        const uint32_t tk = __builtin_amdgcn_readlane(taken, (int)(j >> 5));
                        if ((tk >> (j & 31)) & 1u) dropped = true;
                    }
                }
                if (dropped) {
                    const int w = (int)(i >> 5);
                    if (lane == w) taken &= ~((uint32_t)1 << (i & 31));
                }
            }
        }
    }
    for (uint32_t k = 256; k < ncf; ++k) {
        const uint32_t i = conf_rows[k];
        const uint64_t nf = sinfo[(size_t)b * PREFIX + i];
        const uint32_t cnt = (uint32_t)(nf >> 60);
        bool dropped = false;
        if (cnt == 6) {
            const uint32_t* row = mbase + (size_t)i * 64;
            const int iw = i >> 5;
            for (int w = 0; w <= iw; ++w) {
                uint32_t bits = row[w];
                if (w == iw) bits &= (((uint32_t)1 << (i & 31)) - 1u);
                const uint32_t tk = __builtin_amdgcn_readlane(taken, w);
                if (bits & tk) { dropped = true; break; }
            }
        } else {
            uint64_t p = nf;
            for (uint32_t c = 0; c < cnt; ++c) {
                const uint32_t j = (uint32_t)(p & 0xFFFu);
                p >>= 12;
                const uint32_t tk = __builtin_amdgcn_readlane(taken, (int)(j >> 5));
                if ((tk >> (j & 31)) & 1u) dropped = true;
            }
        }
        if (dropped) {
            const int w = (int)(i >> 5);
            if (lane == w) taken &= ~((uint32_t)1 << (i & 31));
        }
    }

    const uint32_t tpc = (uint32_t)__popc(taken);
    uint32_t tpref = tpc;
    for (int d = 1; d < 64; d <<= 1) {
        const uint32_t v = __shfl_up(tpref, d);
        if (lane >= d) tpref += v;
    }
    const uint32_t total = __shfl(tpref, 63);
    uint32_t rank = tpref - tpc;
    uint32_t w = taken;
    while (w) {
        const int q = __ffs(w) - 1;
        w &= w - 1;
        if (rank < (uint32_t)NPROP)
            kept_idx[(size_t)b * NPROP + rank] = (uint32_t)(lane * 32 + q);
        ++rank;
    }
    if (lane == 0) meta[MT_KEPT + b] = min(total, (uint32_t)NPROP);
}

__global__ __launch_bounds__(1024) void k_finish(const float4* __restrict__ boxes,
        uint32_t* meta, uint32_t* kept_idx, float4* __restrict__ out) {
    const int b = blockIdx.x;
    const float4* bx = boxes + (size_t)b * K_PRE;
    __shared__ float4 kb[NPROP];
    __shared__ uint32_t sflag;
    uint32_t kept = meta[MT_KEPT + b];
    if (kept < NPROP) {
        for (uint32_t k = threadIdx.x; k < kept; k += 1024)
            kb[k] = bx[kept_idx[(size_t)b * NPROP + k]];
        __syncthreads();
        for (int i = PREFIX; i < K_PRE && kept < NPROP; ++i) {
            if (threadIdx.x == 0) sflag = 0;
            __syncthreads();
            const float4 c = bx[i];
            const float areaC = (c.z - c.x) * (c.w - c.y);
            bool sup = false;
            for (uint32_t k = threadIdx.x; k < kept; k += 1024) {
                const float4 a = kb[k];
                const float yy1 = fmaxf(c.x, a.x), xx1 = fmaxf(c.y, a.y);
                const float yy2 = fminf(c.z, a.z), xx2 = fminf(c.w, a.w);
                const float inter = fmaxf(yy2 - yy1, 0.0f) * fmaxf(xx2 - xx1, 0.0f);
                const float areaA = (a.z - a.x) * (a.w - a.y);
                const float uni = fmaxf(areaC + areaA - inter, 1e-8f);
                if (inter / uni > NMS_THR) { sup = true; break; }
            }
            if (sup) atomicOr(&sflag, 1u);
            __syncthreads();
            if (sflag == 0) {
                if (threadIdx.x == 0) {
                    kept_idx[(size_t)b * NPROP + kept] = (uint32_t)i;
                    kb[kept] = c;
                }
                ++kept;
            }
            __syncthreads();
        }
        if (threadIdx.x == 0) meta[MT_KEPT + b] = kept;
    }
    __syncthreads();
    for (uint32_t k = threadIdx.x; k < NPROP; k += 1024) {
        float4 v = make_float4(0.f, 0.f, 0.f, 0.f);
        if (k < kept) v = bx[kept_idx[(size_t)b * NPROP + k]];
        out[(size_t)b * NPROP + k] = v;
    }
}

extern "C" void kernel_launch(void* const* d_in, const int* in_sizes, int n_in,
                              void* d_out, int out_size, void* d_ws, size_t ws_size,
                              hipStream_t stream) {
    const float4* probs4 = (const float4*)d_in[0];
    const float4* bbox   = (const float4*)d_in[1];
    const float4* anch   = (const float4*)d_in[2];
    char* ws = (char*)d_ws;
    if (ws_size < (size_t)WS_NEED) return;
    uint32_t* hist1 = (uint32_t*)(ws + HIST1_OFF);
    uint32_t* hist2 = (uint32_t*)(ws + HIST2_OFF);
    uint32_t* meta  = (uint32_t*)(ws + META_OFF);
    uint64_t* cand  = (uint64_t*)(ws + CAND_OFF);
    float4*   boxes = (float4*)(ws + BOXES_OFF);
    uint32_t* mask  = (uint32_t*)(ws + MASK_OFF);
    uint32_t* kidx  = (uint32_t*)(ws + KIDX_OFF);
    uint64_t* candc = (uint64_t*)(ws + CANDC_OFF);
    uint64_t* sinfo = (uint64_t*)(ws + HIST1_OFF);   // reuse: hist1 dead after k_thresh
    uint32_t* cbm   = (uint32_t*)(ws + HIST2_OFF);   // reuse: hist2 dead after k_thresh2f
    uint32_t* ranks = (uint32_t*)(ws + CANDC_OFF);   // reuse: candc dead after k_thresh2f

    k_sample<<<dim3(BATCH), dim3(256), 0, stream>>>(probs4, meta, hist1, hist2);
    k_histc<<<dim3(512), dim3(256), 0, stream>>>(probs4, meta, meta, hist1, candc);
    k_thresh<<<dim3(BATCH), dim3(256), 0, stream>>>(hist1, meta);
    k_hist2s<<<dim3(2048), dim3(256), 0, stream>>>(probs4, meta, hist2, candc);
    k_thresh2f<<<dim3(BATCH), dim3(256), 0, stream>>>(hist2, meta, candc, cand);
    k_rankonly<<<dim3(BATCH), dim3(1024), 0, stream>>>(cand, meta, ranks);
    k_decode<<<dim3(BATCH * 32), dim3(256), 0, stream>>>(cand, meta, ranks, bbox, anch, boxes);
    k_matrix<<<dim3(BATCH * NTILT), dim3(256), 0, stream>>>(boxes, mask);
    k_conflict<<<dim3(BATCH * 8), dim3(256), 0, stream>>>(mask, sinfo, cbm);
    k_greedy<<<dim3(BATCH), dim3(64), 0, stream>>>(mask, sinfo, cbm, meta, kidx);
    k_finish<<<dim3(BATCH), dim3(1024), 0, stream>>>(boxes, meta, kidx, (float4*)d_out);
}

// Round 16
// 147.284 us; speedup vs baseline: 1.0735x; 1.0735x over previous
//
#include <hip/hip_runtime.h>
#include <stdint.h>

#define BATCH 8
#define NN 262144
#define K_PRE 6000
#define NPROP 1000
#define NMS_THR 0.7f
#define CAND_CAP 8192
#define CANDC_CAP 16384
#define PREFIX 2048
#define NB1 16384
#define NB2 4096
#define RBINS 4096
#define TSAMP 688      // sample-count target: ~11000 actual admitted (x16 scale)
#define NTILT 528      // lower-triangle tiles: 32*33/2

// meta u32 indices
#define MT_T2 0        // [0..7]   final threshold
#define MT_KEPT 16     // [16..23] kept count
#define MT_T1 24       // [24..31] coarse bucket
#define MT_CUM 32      // [32..39] cum count above coarse bucket
#define MT_TG 40       // [40..47] speculative stash threshold
#define MT_VALID 48    // [48..55] stash validity flag
#define MT_OVF 56      // [56..63] local-stash overflow flag
#define MT_CNT(b)   (64 + 32*(b))       // exact candidate count
#define MT_CNTC(b)  (64 + 32*(b) + 16)  // pass-1 stash count
#define MT_CNTC2(b) (64 + 32*(b) + 24)  // fallback stash count

// workspace layout (bytes)
#define HIST1_OFF 0                                   // BATCH*NB1*4 = 524288
#define HIST2_OFF (HIST1_OFF + BATCH*NB1*4)           // + BATCH*NB2*4 = 131072
#define META_OFF  (HIST2_OFF + BATCH*NB2*4)           // 2048 B
#define CAND_OFF  (META_OFF + 2048)
#define BOXES_OFF (CAND_OFF + BATCH*CAND_CAP*8)       // BATCH*K_PRE*16
#define MASK_OFF  (BOXES_OFF + BATCH*K_PRE*16)        // BATCH*PREFIX*64*4 = 4 MB
#define KIDX_OFF  (MASK_OFF + (size_t)BATCH*PREFIX*64*4)
#define CANDC_OFF (KIDX_OFF + BATCH*NPROP*4)          // BATCH*CANDC_CAP*8 = 1 MB
#define WS_NEED   (CANDC_OFF + (size_t)BATCH*CANDC_CAP*8)

// region reuse:
//  - sinfo (u64[BATCH*PREFIX] = 128KB) -> HIST1 region (dead after k_thresh)
//  - cbm (u32[BATCH*64] = 2KB)         -> HIST2 region (dead after k_thresh2f)
//  - ranks (u32[BATCH*CAND_CAP])       -> CANDC region (dead after k_thresh2f)

__device__ __forceinline__ uint32_t fkey(float f) {
    uint32_t b = __float_as_uint(f);
    return b ^ (uint32_t)(((int32_t)b >> 31) | 0x80000000u);
}

// Per-batch: zero hists/counters + sample 16384 scores to pick speculative
// stash threshold Tg (~11K admitted; errors caught by validity -> fallback).
__global__ __launch_bounds__(256) void k_sample(const float4* __restrict__ probs4,
        uint32_t* meta, uint32_t* __restrict__ hist1, uint32_t* __restrict__ hist2) {
    __shared__ uint32_t h[NB1];
    __shared__ uint32_t part[256];
    const int b = blockIdx.x;
    uint32_t* gh1 = hist1 + (size_t)b * NB1;
    uint32_t* gh2 = hist2 + (size_t)b * NB2;
    for (int i = threadIdx.x; i < NB1; i += 256) { gh1[i] = 0; h[i] = 0; }
    for (int i = threadIdx.x; i < NB2; i += 256) gh2[i] = 0;
    if (threadIdx.x == 0) {
        meta[MT_CNTC(b)] = 0;
        meta[MT_CNTC2(b)] = 0;
        meta[MT_OVF + b] = 0;
    }
    __syncthreads();
    const float4* p = probs4 + (size_t)b * (NN / 2);
    for (int c = 0; c < 16; ++c) {
        const float4* pc = p + c * (NN / 2 / 16);
        for (int i = threadIdx.x; i < 512; i += 256) {
            const float4 v = pc[i];
            atomicAdd(&h[fkey(v.y) >> 18], 1u);
            atomicAdd(&h[fkey(v.w) >> 18], 1u);
        }
    }
    __syncthreads();
    const int t = threadIdx.x;
    uint32_t s = 0;
    const int hi = NB1 - 64 * t;
    for (int i = hi - 64; i < hi; ++i) s += h[i];
    part[t] = s;
    __syncthreads();
    if (t == 0) {
        uint32_t cum = 0;
        int strip = 0;
        for (; strip < 256; ++strip) {
            if (cum + part[strip] >= (uint32_t)TSAMP) break;
            cum += part[strip];
        }
        int B = 0;
        if (strip < 256) {
            const int top = NB1 - 64 * strip;
            int i = top - 1;
            for (; i >= top - 64; --i) {
                if (cum + h[i] >= (uint32_t)TSAMP) break;
                cum += h[i];
            }
            if (i < top - 64) i = top - 64;
            B = i;
        }
        meta[MT_TG + b] = (uint32_t)B << 18;
    }
}

// THE single full 16.8MB pass: 16K-bin histogram + speculative stash.
// LDS budget: 64KB hist + 8KB stash = 72KB -> 2 blocks/CU (80KB would drop
// to 1 block/CU: 2x80KB exceeds 160KB by 16 bytes -- the R15 regression).
// Stash cap 1024 vs expected 172/block (+60 sigma); overflow -> exact fallback.
__global__ __launch_bounds__(256) void k_histc(const float4* __restrict__ probs4,
        const uint32_t* __restrict__ meta_r, uint32_t* meta_w,
        uint32_t* __restrict__ hist, uint64_t* __restrict__ cand_c) {
    __shared__ uint32_t h[NB1];        // 64 KB
    __shared__ uint64_t stash[1024];   // 8 KB
    __shared__ uint32_t lcnt, lbase;
    for (int i = threadIdx.x; i < NB1; i += 256) h[i] = 0;
    if (threadIdx.x == 0) lcnt = 0;
    __syncthreads();
    const int b = blockIdx.x >> 6;
    const int s = blockIdx.x & 63;
    const uint32_t Tg = meta_r[MT_TG + b];
    const float4* p = probs4 + (size_t)b * (NN / 2) + (size_t)s * 2048;
    const uint32_t base_n = (uint32_t)s * 4096;
    for (int i = threadIdx.x; i < 2048; i += 256) {
        const float4 v = p[i];
        const uint32_t u1 = fkey(v.y), u2 = fkey(v.w);
        atomicAdd(&h[u1 >> 18], 1u);
        atomicAdd(&h[u2 >> 18], 1u);
        if (u1 >= Tg) {
            const uint32_t pos = atomicAdd(&lcnt, 1u);
            if (pos < 1024) stash[pos] = ((uint64_t)u1 << 32) | (uint32_t)(~(base_n + 2u * (uint32_t)i));
        }
        if (u2 >= Tg) {
            const uint32_t pos = atomicAdd(&lcnt, 1u);
            if (pos < 1024) stash[pos] = ((uint64_t)u2 << 32) | (uint32_t)(~(base_n + 2u * (uint32_t)i + 1u));
        }
    }
    __syncthreads();
    uint32_t* gh = hist + (size_t)b * NB1;
    for (int i = threadIdx.x; i < NB1; i += 256)
        if (h[i]) atomicAdd(&gh[i], h[i]);
    if (threadIdx.x == 0) {
        if (lcnt > 1024) atomicOr(&meta_w[MT_OVF + b], 1u);
        lbase = atomicAdd(&meta_w[MT_CNTC(b)], min(lcnt, 1024u));
    }
    __syncthreads();
    uint64_t* cc = cand_c + (size_t)b * CANDC_CAP;
    const uint32_t n_loc = min(lcnt, 1024u), base = lbase;
    for (uint32_t i = threadIdx.x; i < n_loc; i += 256) {
        const uint32_t pos = base + i;
        if (pos < CANDC_CAP) cc[pos] = stash[i];
    }
}

__global__ __launch_bounds__(256) void k_thresh(const uint32_t* __restrict__ hist,
                                                uint32_t* meta) {
    const int b = blockIdx.x;
    const uint32_t* gh = hist + (size_t)b * NB1;
    __shared__ uint32_t part[256];
    const int t = threadIdx.x;
    uint32_t s = 0;
    const int hi = NB1 - 64 * t;
    for (int i = hi - 64; i < hi; ++i) s += gh[i];
    part[t] = s;
    __syncthreads();
    if (t == 0) {
        uint32_t cum = 0;
        int strip = 0;
        for (; strip < 256; ++strip) {
            if (cum + part[strip] >= (uint32_t)K_PRE) break;
            cum += part[strip];
        }
        int t1 = 0;
        if (strip < 256) {
            const int top = NB1 - 64 * strip;
            int i = top - 1;
            for (; i >= top - 64; --i) {
                const uint32_t c = gh[i];
                if (cum + c >= (uint32_t)K_PRE) break;
                cum += c;
            }
            if (i < top - 64) i = top - 64;
            t1 = i;
        }
        meta[MT_T1 + b] = (uint32_t)t1;
        meta[MT_CUM + b] = cum;
        const uint32_t Tg = meta[MT_TG + b];
        const uint32_t cc = meta[MT_CNTC(b)];
        const uint32_t ovf = meta[MT_OVF + b];
        meta[MT_VALID + b] =
            ((Tg >> 18) <= (uint32_t)t1 && cc <= (uint32_t)CANDC_CAP && !ovf) ? 1u : 0u;
    }
}

// Fine histogram of bucket t1. Valid stash: built from ~88KB stash (1 block/
// batch). Invalid: full probs fallback pass that also re-stashes (cntc2).
__global__ __launch_bounds__(256) void k_hist2s(const float4* __restrict__ probs4,
        uint32_t* meta, uint32_t* __restrict__ hist2, uint64_t* __restrict__ cand_c) {
    __shared__ uint32_t shmem[NB2];    // 16 KB (aliased as stash in fallback)
    const int b = blockIdx.x >> 8;
    const int s = blockIdx.x & 255;
    const uint32_t valid = meta[MT_VALID + b];
    const uint32_t t1 = meta[MT_T1 + b];
    uint32_t* gh = hist2 + (size_t)b * NB2;
    if (valid) {
        if (s != 0) return;
        for (int i = threadIdx.x; i < NB2; i += 256) shmem[i] = 0;
        __syncthreads();
        const uint64_t* cc = cand_c + (size_t)b * CANDC_CAP;
        const uint32_t mc = meta[MT_CNTC(b)];
        for (uint32_t i = threadIdx.x; i < mc; i += 256) {
            const uint32_t khi = (uint32_t)(cc[i] >> 32);
            if ((khi >> 18) == t1) atomicAdd(&shmem[(khi >> 6) & 0xFFFu], 1u);
        }
        __syncthreads();
        for (int i = threadIdx.x; i < NB2; i += 256)
            if (shmem[i]) gh[i] = shmem[i];   // hist2 pre-zeroed; single writer
    } else {
        uint64_t* stash = (uint64_t*)shmem;   // 1024 u64 = 8 KB
        __shared__ uint32_t lcnt, lbase;
        const uint32_t Tc = t1 << 18;
        if (threadIdx.x == 0) lcnt = 0;
        __syncthreads();
        const float4* p = probs4 + (size_t)b * (NN / 2) + (size_t)s * 512;
        const uint32_t base_n = (uint32_t)s * 1024;
        for (int i = threadIdx.x; i < 512; i += 256) {
            const float4 v = p[i];
            const uint32_t u1 = fkey(v.y), u2 = fkey(v.w);
            if ((u1 >> 18) == t1) atomicAdd(&gh[(u1 >> 6) & 0xFFFu], 1u);
            if ((u2 >> 18) == t1) atomicAdd(&gh[(u2 >> 6) & 0xFFFu], 1u);
            if (u1 >= Tc) {
                const uint32_t pos = atomicAdd(&lcnt, 1u);
                if (pos < 1024) stash[pos] = ((uint64_t)u1 << 32) | (uint32_t)(~(base_n + 2u * (uint32_t)i));
            }
            if (u2 >= Tc) {
                const uint32_t pos = atomicAdd(&lcnt, 1u);
                if (pos < 1024) stash[pos] = ((uint64_t)u2 << 32) | (uint32_t)(~(base_n + 2u * (uint32_t)i + 1u));
            }
        }
        __syncthreads();
        if (threadIdx.x == 0) lbase = atomicAdd(&meta[MT_CNTC2(b)], min(lcnt, 1024u));
        __syncthreads();
        uint64_t* cc = cand_c + (size_t)b * CANDC_CAP;
        const uint32_t n_loc = min(lcnt, 1024u), base = lbase;
        for (uint32_t i = threadIdx.x; i < n_loc; i += 256) {
            const uint32_t pos = base + i;
            if (pos < CANDC_CAP) cc[pos] = stash[i];
        }
    }
}

// Fused: fine-threshold T2 selection + stash filter -> exact candidate set.
__global__ __launch_bounds__(256) void k_thresh2f(const uint32_t* __restrict__ hist2,
        uint32_t* meta, const uint64_t* __restrict__ cand_c, uint64_t* __restrict__ cand) {
    const int b = blockIdx.x;
    const uint32_t* gh = hist2 + (size_t)b * NB2;
    __shared__ uint32_t part[256];
    __shared__ uint32_t sT2, scnt;
    const int t = threadIdx.x;
    uint32_t s = 0;
    const int hi = NB2 - 16 * t;
    for (int i = hi - 16; i < hi; ++i) s += gh[i];
    part[t] = s;
    __syncthreads();
    if (t == 0) {
        const uint32_t t1 = meta[MT_T1 + b];
        uint32_t cum = meta[MT_CUM + b];
        int strip = 0;
        for (; strip < 256; ++strip) {
            if (cum + part[strip] >= (uint32_t)K_PRE) break;
            cum += part[strip];
        }
        int sub = 0;
        if (strip < 256) {
            const int top = NB2 - 16 * strip;
            int i = top - 1;
            for (; i >= top - 16; --i) {
                const uint32_t c = gh[i];
                if (cum + c >= (uint32_t)K_PRE) break;
                cum += c;
            }
            if (i < top - 16) i = top - 16;
            sub = i;
        }
        sT2 = (t1 << 18) | ((uint32_t)sub << 6);
        meta[MT_T2 + b] = sT2;
        meta[MT_KEPT + b] = 0;
        scnt = 0;
    }
    __syncthreads();
    const uint32_t T = sT2;
    const uint32_t valid = meta[MT_VALID + b];
    const uint32_t mc = min(valid ? meta[MT_CNTC(b)] : meta[MT_CNTC2(b)], (uint32_t)CANDC_CAP);
    const uint64_t* cc = cand_c + (size_t)b * CANDC_CAP;
    uint64_t* cb = cand + (size_t)b * CAND_CAP;
    for (uint32_t i = (uint32_t)t; i < mc; i += 256) {
        const uint64_t k = cc[i];
        if ((uint32_t)(k >> 32) >= T) {
            const uint32_t pos = atomicAdd(&scnt, 1u);
            if (pos < CAND_CAP) cb[pos] = k;
        }
    }
    __syncthreads();
    if (t == 0) meta[MT_CNT(b)] = scnt;
}

// Rank via monotone binning + suffix scan + within-bin exact compare.
__global__ __launch_bounds__(1024) void k_rankonly(const uint64_t* __restrict__ cand,
        const uint32_t* __restrict__ meta, uint32_t* __restrict__ ranks) {
    __shared__ uint64_t skey[CAND_CAP];
    __shared__ uint16_t sbin[CAND_CAP];
    __shared__ uint32_t cnt[RBINS];
    __shared__ uint32_t S[RBINS];
    __shared__ uint16_t order[CAND_CAP];
    __shared__ uint32_t sc[1024];
    const int b = blockIdx.x;
    const int t = threadIdx.x;
    const uint32_t m = min(meta[MT_CNT(b)], (uint32_t)CAND_CAP);
    const uint32_t T2 = meta[MT_T2 + b];
    const uint32_t R = 0xBF800000u - T2;
    const int w = 32 - __clz(R | 1);
    const int sh = (w > 12) ? (w - 12) : 0;
    for (int i = t; i < RBINS; i += 1024) cnt[i] = 0;
    __syncthreads();
    const uint64_t* cb = cand + (size_t)b * CAND_CAP;
    for (uint32_t i = t; i < m; i += 1024) {
        const uint64_t k = cb[i];
        skey[i] = k;
        uint32_t bin = (((uint32_t)(k >> 32)) - T2) >> sh;
        if (bin >= RBINS) bin = RBINS - 1;
        sbin[i] = (uint16_t)bin;
        atomicAdd(&cnt[bin], 1u);
    }
    __syncthreads();
    const uint32_t c1 = cnt[4 * t + 1], c2 = cnt[4 * t + 2], c3 = cnt[4 * t + 3];
    sc[t] = cnt[4 * t] + c1 + c2 + c3;
    __syncthreads();
    for (int d = 1; d < 1024; d <<= 1) {
        const uint32_t v = (t + d < 1024) ? sc[t + d] : 0;
        __syncthreads();
        sc[t] += v;
        __syncthreads();
    }
    const uint32_t Spart = (t + 1 < 1024) ? sc[t + 1] : 0;
    S[4 * t + 3] = Spart;
    S[4 * t + 2] = Spart + c3;
    S[4 * t + 1] = Spart + c3 + c2;
    S[4 * t + 0] = Spart + c3 + c2 + c1;
    __syncthreads();
    for (uint32_t i = t; i < m; i += 1024) {
        const uint32_t bin = sbin[i];
        const uint32_t intra = atomicSub(&cnt[bin], 1u) - 1u;
        order[S[bin] + intra] = (uint16_t)i;
    }
    __syncthreads();
    uint32_t* rb = ranks + (size_t)b * CAND_CAP;
    for (uint32_t i = t; i < m; i += 1024) {
        const uint32_t bin = sbin[i];
        const uint64_t ki = skey[i];
        const uint32_t start = S[bin];
        const uint32_t end = (bin > 0) ? S[bin - 1] : m;
        uint32_t rank = start;
        for (uint32_t s2 = start; s2 < end; ++s2)
            if (skey[order[s2]] > ki) ++rank;
        rb[i] = rank;
    }
}

// Decode gather with full parallelism (256 blocks).
__global__ __launch_bounds__(256) void k_decode(const uint64_t* __restrict__ cand,
        const uint32_t* __restrict__ meta, const uint32_t* __restrict__ ranks,
        const float4* __restrict__ bbox, const float4* __restrict__ anch,
        float4* __restrict__ boxes) {
    const int b = blockIdx.x >> 5;
    const int i = ((blockIdx.x & 31) << 8) + threadIdx.x;
    const uint32_t m = min(meta[MT_CNT(b)], (uint32_t)CAND_CAP);
    if ((uint32_t)i >= m) return;
    const uint32_t rank = ranks[(size_t)b * CAND_CAP + i];
    if (rank >= (uint32_t)K_PRE) return;
    const uint64_t ki = cand[(size_t)b * CAND_CAP + i];
    const uint32_t n = ~((uint32_t)ki);
    const float4 a = anch[(size_t)b * NN + n];
    const float4 d = bbox[(size_t)b * NN + n];
    float h = a.z - a.x, w = a.w - a.y;
    const float cy0 = a.x + 0.5f * h + d.x * 0.1f * h;
    const float cx0 = a.y + 0.5f * w + d.y * 0.1f * w;
    h = h * expf(d.z * 0.2f);
    w = w * expf(d.w * 0.2f);
    float4 o;
    o.x = fminf(fmaxf(cy0 - 0.5f * h, 0.0f), 1.0f);
    o.y = fminf(fmaxf(cx0 - 0.5f * w, 0.0f), 1.0f);
    o.z = fminf(fmaxf(cy0 + 0.5f * h, 0.0f), 1.0f);
    o.w = fminf(fmaxf(cx0 + 0.5f * w, 0.0f), 1.0f);
    boxes[(size_t)b * K_PRE + rank] = o;
}

// IoU bit-matrix, LOWER TRIANGLE tiles only (tj <= ti).
__global__ __launch_bounds__(256) void k_matrix(const float4* __restrict__ boxes,
                                                uint32_t* __restrict__ mask) {
    const int b = blockIdx.x / NTILT;
    const int idx = blockIdx.x - b * NTILT;
    int ti = (int)((sqrtf(8.0f * (float)idx + 1.0f) - 1.0f) * 0.5f);
    while ((ti + 1) * (ti + 2) / 2 <= idx) ++ti;
    while (ti * (ti + 1) / 2 > idx) --ti;
    const int tj = idx - ti * (ti + 1) / 2;
    __shared__ float4 rb[64], cb[64];
    __shared__ uint32_t wbits[128];
    const float4* bx = boxes + (size_t)b * K_PRE;
    const int t = threadIdx.x;
    if (t < 64) rb[t] = bx[ti * 64 + t];
    else if (t < 128) cb[t - 64] = bx[tj * 64 + (t - 64)];
    if (t < 128) wbits[t] = 0;
    __syncthreads();
    const int r = t >> 2;
    const int cq = t & 3;
    const float4 a = rb[r];
    const float areaA = (a.z - a.x) * (a.w - a.y);
    uint32_t bits = 0;
#pragma unroll
    for (int jj = 0; jj < 16; ++jj) {
        const float4 cc = cb[cq * 16 + jj];
        const float yy1 = fmaxf(a.x, cc.x), xx1 = fmaxf(a.y, cc.y);
        const float yy2 = fminf(a.z, cc.z), xx2 = fminf(a.w, cc.w);
        const float inter = fmaxf(yy2 - yy1, 0.0f) * fmaxf(xx2 - xx1, 0.0f);
        const float areaC = (cc.z - cc.x) * (cc.w - cc.y);
        const float uni = fmaxf(areaA + areaC - inter, 1e-8f);
        if (inter / uni > NMS_THR) bits |= (1u << jj);
    }
    atomicOr(&wbits[r * 2 + (cq >> 1)], bits << ((cq & 1) * 16));
    __syncthreads();
    if (t < 128) {
        const int rr = t >> 1, ww = t & 1;
        mask[((size_t)b * PREFIX + ti * 64 + rr) * 64 + tj * 2 + ww] = wbits[rr * 2 + ww];
    }
}

// Conflict extraction (lower triangle only; words > iw masked).
__global__ __launch_bounds__(256) void k_conflict(const uint32_t* __restrict__ mask,
        uint64_t* __restrict__ sinfo, uint32_t* __restrict__ cbm) {
    const int b = blockIdx.x >> 3;
    const int s = blockIdx.x & 7;
    const int i = (s << 8) + threadIdx.x;
    const uint4* row4 = (const uint4*)(mask + ((size_t)b * PREFIX + i) * 64);
    const int iw = i >> 5;
    const uint32_t tailmask = ((uint32_t)1 << (i & 31)) - 1u;
    uint32_t cnt = 0;
    uint64_t packed = 0;
    for (int c = 0; c <= (iw >> 2); ++c) {
        const uint4 q = row4[c];
        uint32_t ws[4] = {q.x, q.y, q.z, q.w};
#pragma unroll
        for (int k = 0; k < 4; ++k) {
            const int w = c * 4 + k;
            uint32_t bits = ws[k];
            if (w > iw) bits = 0;
            else if (w == iw) bits &= tailmask;
            while (bits) {
                const int bp = __ffs(bits) - 1;
                bits &= bits - 1;
                if (cnt < 5) packed |= (uint64_t)(uint32_t)(w * 32 + bp) << (12 * cnt);
                ++cnt;
            }
        }
    }
    packed |= (uint64_t)(cnt <= 5 ? cnt : 6) << 60;
    sinfo[(size_t)b * PREFIX + i] = packed;
    const unsigned long long bm = __ballot(cnt != 0);
    const int wv = threadIdx.x >> 6;
    const int lid = threadIdx.x & 63;
    if (lid == 0) cbm[(size_t)b * 64 + (s << 3) + wv * 2] = (uint32_t)bm;
    else if (lid == 1) cbm[(size_t)b * 64 + (s << 3) + wv * 2 + 1] = (uint32_t)(bm >> 32);
}

// Greedy resolution via conflicted-row sparse resolve.
__global__ __launch_bounds__(64) void k_greedy(const uint32_t* __restrict__ mask,
        const uint64_t* __restrict__ sinfo, const uint32_t* __restrict__ cbm,
        uint32_t* meta, uint32_t* __restrict__ kept_idx) {
    __shared__ uint32_t conf_rows[PREFIX];
    __shared__ uint32_t ncf_s;
    const int b = blockIdx.x;
    const int lane = threadIdx.x;
    const uint32_t cw = cbm[(size_t)b * 64 + lane];
    uint32_t taken = 0xFFFFFFFFu;

    const uint32_t pc = (uint32_t)__popc(cw);
    uint32_t pref = pc;
    for (int d = 1; d < 64; d <<= 1) {
        const uint32_t v = __shfl_up(pref, d);
        if (lane >= d) pref += v;
    }
    const uint32_t ncf = __shfl(pref, 63);
    uint32_t idx = pref - pc;
    uint32_t tm = cw;
    while (tm) {
        const int q = __ffs(tm) - 1;
        tm &= tm - 1;
        conf_rows[idx] = (uint32_t)(lane * 32 + q);
        ++idx;
    }
    if (lane == 0) ncf_s = ncf;
    __syncthreads();

    uint32_t r_i[4], r_lo[4], r_hi[4];
#pragma unroll
    for (int r = 0; r < 4; ++r) {
        const uint32_t k = (uint32_t)(r * 64 + lane);
        const uint32_t ri = (k < ncf) ? conf_rows[k] : 0;
        const uint64_t nf = (k < ncf) ? sinfo[(size_t)b * PREFIX + ri] : 0ull;
        r_i[r] = ri;
        r_lo[r] = (uint32_t)nf;
        r_hi[r] = (uint32_t)(nf >> 32);
    }

    const uint32_t* mbase = mask + (size_t)b * PREFIX * 64;

#pragma unroll
    for (int seg = 0; seg < 4; ++seg) {
        const uint32_t segbase = (uint32_t)(seg * 64);
        if (segbase < ncf) {
            const uint32_t segcnt = min(64u, ncf - segbase);
            for (uint32_t k2 = 0; k2 < segcnt; ++k2) {
                const uint32_t i  = __builtin_amdgcn_readlane(r_i[seg], (int)k2);
                const uint32_t lo = __builtin_amdgcn_readlane(r_lo[seg], (int)k2);
                const uint32_t hi = __builtin_amdgcn_readlane(r_hi[seg], (int)k2);
                const uint32_t cnt = hi >> 28;
                bool dropped = false;
                if (cnt == 6) {
                    const uint32_t* row = mbase + (size_t)i * 64;
                    const int iw = i >> 5;
                    for (int w = 0; w <= iw; ++w) {
                        uint32_t bits = row[w];
                        if (w == iw) bits &= (((uint32_t)1 << (i & 31)) - 1u);
                        const uint32_t tk = __builtin_amdgcn_readlane(taken, w);
                        if (bits & tk) { dropped = true; break; }
                    }
                } else {
                    uint64_t p = ((uint64_t)hi << 32) | lo;
                    for (uint32_t c = 0; c < cnt; ++c) {
                        const uint32_t j = (uint32_t)(p & 0xFFFu);
                        p >>= 12;
                        const uint32_t tk = __builtin_amdgcn_readlane(taken, (int)(j >> 5));
                        if ((tk >> (j & 31)) & 1u) dropped = true;
                    }
                }
                if (dropped) {
                    const int w = (int)(i >> 5);
                    if (lane == w) taken &= ~((uint32_t)1 << (i & 31));
                }
            }
        }
    }
    for (uint32_t k = 256; k < ncf; ++k) {
        const uint32_t i = conf_rows[k];
        const uint64_t nf = sinfo[(size_t)b * PREFIX + i];
        const uint32_t cnt = (uint32_t)(nf >> 60);
        bool dropped = false;
        if (cnt == 6) {
            const uint32_t* row = mbase + (size_t)i * 64;
            const int iw = i >> 5;
            for (int w = 0; w <= iw; ++w) {
                uint32_t bits = row[w];
                if (w == iw) bits &= (((uint32_t)1 << (i & 31)) - 1u);
                const uint32_t tk = __builtin_amdgcn_readlane(taken, w);
                if (bits & tk) { dropped = true; break; }
            }
        } else {
            uint64_t p = nf;
            for (uint32_t c = 0; c < cnt; ++c) {
                const uint32_t j = (uint32_t)(p & 0xFFFu);
                p >>= 12;
                const uint32_t tk = __builtin_amdgcn_readlane(taken, (int)(j >> 5));
                if ((tk >> (j & 31)) & 1u) dropped = true;
            }
        }
        if (dropped) {
            const int w = (int)(i >> 5);
            if (lane == w) taken &= ~((uint32_t)1 << (i & 31));
        }
    }

    const uint32_t tpc = (uint32_t)__popc(taken);
    uint32_t tpref = tpc;
    for (int d = 1; d < 64; d <<= 1) {
        const uint32_t v = __shfl_up(tpref, d);
        if (lane >= d) tpref += v;
    }
    const uint32_t total = __shfl(tpref, 63);
    uint32_t rank = tpref - tpc;
    uint32_t w = taken;
    while (w) {
        const int q = __ffs(w) - 1;
        w &= w - 1;
        if (rank < (uint32_t)NPROP)
            kept_idx[(size_t)b * NPROP + rank] = (uint32_t)(lane * 32 + q);
        ++rank;
    }
    if (lane == 0) meta[MT_KEPT + b] = min(total, (uint32_t)NPROP);
}

__global__ __launch_bounds__(1024) void k_finish(const float4* __restrict__ boxes,
        uint32_t* meta, uint32_t* kept_idx, float4* __restrict__ out) {
    const int b = blockIdx.x;
    const float4* bx = boxes + (size_t)b * K_PRE;
    __shared__ float4 kb[NPROP];
    __shared__ uint32_t sflag;
    uint32_t kept = meta[MT_KEPT + b];
    if (kept < NPROP) {
        for (uint32_t k = threadIdx.x; k < kept; k += 1024)
            kb[k] = bx[kept_idx[(size_t)b * NPROP + k]];
        __syncthreads();
        for (int i = PREFIX; i < K_PRE && kept < NPROP; ++i) {
            if (threadIdx.x == 0) sflag = 0;
            __syncthreads();
            const float4 c = bx[i];
            const float areaC = (c.z - c.x) * (c.w - c.y);
            bool sup = false;
            for (uint32_t k = threadIdx.x; k < kept; k += 1024) {
                const float4 a = kb[k];
                const float yy1 = fmaxf(c.x, a.x), xx1 = fmaxf(c.y, a.y);
                const float yy2 = fminf(c.z, a.z), xx2 = fminf(c.w, a.w);
                const float inter = fmaxf(yy2 - yy1, 0.0f) * fmaxf(xx2 - xx1, 0.0f);
                const float areaA = (a.z - a.x) * (a.w - a.y);
                const float uni = fmaxf(areaC + areaA - inter, 1e-8f);
                if (inter / uni > NMS_THR) { sup = true; break; }
            }
            if (sup) atomicOr(&sflag, 1u);
            __syncthreads();
            if (sflag == 0) {
                if (threadIdx.x == 0) {
                    kept_idx[(size_t)b * NPROP + kept] = (uint32_t)i;
                    kb[kept] = c;
                }
                ++kept;
            }
            __syncthreads();
        }
        if (threadIdx.x == 0) meta[MT_KEPT + b] = kept;
    }
    __syncthreads();
    for (uint32_t k = threadIdx.x; k < NPROP; k += 1024) {
        float4 v = make_float4(0.f, 0.f, 0.f, 0.f);
        if (k < kept) v = bx[kept_idx[(size_t)b * NPROP + k]];
        out[(size_t)b * NPROP + k] = v;
    }
}

extern "C" void kernel_launch(void* const* d_in, const int* in_sizes, int n_in,
                              void* d_out, int out_size, void* d_ws, size_t ws_size,
                              hipStream_t stream) {
    const float4* probs4 = (const float4*)d_in[0];
    const float4* bbox   = (const float4*)d_in[1];
    const float4* anch   = (const float4*)d_in[2];
    char* ws = (char*)d_ws;
    if (ws_size < (size_t)WS_NEED) return;
    uint32_t* hist1 = (uint32_t*)(ws + HIST1_OFF);
    uint32_t* hist2 = (uint32_t*)(ws + HIST2_OFF);
    uint32_t* meta  = (uint32_t*)(ws + META_OFF);
    uint64_t* cand  = (uint64_t*)(ws + CAND_OFF);
    float4*   boxes = (float4*)(ws + BOXES_OFF);
    uint32_t* mask  = (uint32_t*)(ws + MASK_OFF);
    uint32_t* kidx  = (uint32_t*)(ws + KIDX_OFF);
    uint64_t* candc = (uint64_t*)(ws + CANDC_OFF);
    uint64_t* sinfo = (uint64_t*)(ws + HIST1_OFF);   // reuse: hist1 dead after k_thresh
    uint32_t* cbm   = (uint32_t*)(ws + HIST2_OFF);   // reuse: hist2 dead after k_thresh2f
    uint32_t* ranks = (uint32_t*)(ws + CANDC_OFF);   // reuse: candc dead after k_thresh2f

    k_sample<<<dim3(BATCH), dim3(256), 0, stream>>>(probs4, meta, hist1, hist2);
    k_histc<<<dim3(512), dim3(256), 0, stream>>>(probs4, meta, meta, hist1, candc);
    k_thresh<<<dim3(BATCH), dim3(256), 0, stream>>>(hist1, meta);
    k_hist2s<<<dim3(2048), dim3(256), 0, stream>>>(probs4, meta, hist2, candc);
    k_thresh2f<<<dim3(BATCH), dim3(256), 0, stream>>>(hist2, meta, candc, cand);
    k_rankonly<<<dim3(BATCH), dim3(1024), 0, stream>>>(cand, meta, ranks);
    k_decode<<<dim3(BATCH * 32), dim3(256), 0, stream>>>(cand, meta, ranks, bbox, anch, boxes);
    k_matrix<<<dim3(BATCH * NTILT), dim3(256), 0, stream>>>(boxes, mask);
    k_conflict<<<dim3(BATCH * 8), dim3(256), 0, stream>>>(mask, sinfo, cbm);
    k_greedy<<<dim3(BATCH), dim3(64), 0, stream>>>(mask, sinfo, cbm, meta, kidx);
    k_finish<<<dim3(BATCH), dim3(1024), 0, stream>>>(boxes, meta, kidx, (float4*)d_out);
}

// Round 17
// 109.619 us; speedup vs baseline: 1.4423x; 1.3436x over previous
//
#include <hip/hip_runtime.h>
#include <stdint.h>

#define BATCH 8
#define NN 262144
#define K_PRE 6000
#define NPROP 1000
#define NMS_THR 0.7f
#define CAND_CAP 8192
#define CANDC_CAP 16384
#define PREFIX 2048
#define NB1 16384
#define NB2 4096
#define RBINS 4096
#define NTILT 528      // lower-triangle tiles: 32*33/2

// meta u32 indices
#define MT_T2 0        // [0..7]   final threshold
#define MT_KEPT 16     // [16..23] kept count
#define MT_T1 24       // [24..31] coarse bucket
#define MT_CUM 32      // [32..39] cum count above coarse bucket
#define MT_CNT(b)   (64 + 32*(b))       // exact candidate count
#define MT_CNTC(b)  (64 + 32*(b) + 16)  // coarse-stash count

// workspace layout (bytes)
#define HIST1_OFF 0                                   // BATCH*NB1*4 = 524288
#define HIST2_OFF (HIST1_OFF + BATCH*NB1*4)           // + BATCH*NB2*4 = 131072
#define META_OFF  (HIST2_OFF + BATCH*NB2*4)           // 2048 B
#define CAND_OFF  (META_OFF + 2048)
#define BOXES_OFF (CAND_OFF + BATCH*CAND_CAP*8)       // BATCH*K_PRE*16
#define MASK_OFF  (BOXES_OFF + BATCH*K_PRE*16)        // BATCH*PREFIX*64*4 = 4 MB
#define KIDX_OFF  (MASK_OFF + (size_t)BATCH*PREFIX*64*4)
#define CANDC_OFF (KIDX_OFF + BATCH*NPROP*4)          // BATCH*CANDC_CAP*8 = 1 MB
#define WS_NEED   (CANDC_OFF + (size_t)BATCH*CANDC_CAP*8)

// region reuse:
//  - sinfo (u64[BATCH*PREFIX] = 128KB) -> HIST1 region (dead after k_thresh)
//  - cbm (u32[BATCH*64] = 2KB)         -> HIST2 region (dead after k_thresh2f)
//  - ranks (u32[BATCH*CAND_CAP])       -> CANDC region (dead after k_thresh2f)

#define HZERO (BATCH * (NB1 + NB2))                   // u32s of histograms

__device__ __forceinline__ uint32_t fkey(float f) {
    uint32_t b = __float_as_uint(f);
    return b ^ (uint32_t)(((int32_t)b >> 31) | 0x80000000u);
}

__global__ void k_zero(uint32_t* h) {
    const int i = blockIdx.x * 256 + threadIdx.x;
    if (i < HZERO) h[i] = 0;
}

// 512 blocks = 64 per batch; each block: 2048 float4 (= 4096 elements).
__global__ __launch_bounds__(256) void k_hist(const float4* __restrict__ probs4,
                                              uint32_t* __restrict__ hist) {
    __shared__ uint32_t h[NB1];
    for (int i = threadIdx.x; i < NB1; i += 256) h[i] = 0;
    __syncthreads();
    const int b = blockIdx.x >> 6;
    const int s = blockIdx.x & 63;
    const float4* p = probs4 + (size_t)b * (NN / 2) + (size_t)s * 2048;
    for (int i = threadIdx.x; i < 2048; i += 256) {
        const float4 v = p[i];
        atomicAdd(&h[fkey(v.y) >> 18], 1u);
        atomicAdd(&h[fkey(v.w) >> 18], 1u);
    }
    __syncthreads();
    uint32_t* gh = hist + (size_t)b * NB1;
    for (int i = threadIdx.x; i < NB1; i += 256)
        if (h[i]) atomicAdd(&gh[i], h[i]);
}

__global__ __launch_bounds__(256) void k_thresh(const uint32_t* __restrict__ hist,
                                                uint32_t* meta) {
    const int b = blockIdx.x;
    const uint32_t* gh = hist + (size_t)b * NB1;
    __shared__ uint32_t part[256];
    const int t = threadIdx.x;
    uint32_t s = 0;
    const int hi = NB1 - 64 * t;
    for (int i = hi - 64; i < hi; ++i) s += gh[i];
    part[t] = s;
    __syncthreads();
    if (t == 0) {
        uint32_t cum = 0;
        int strip = 0;
        for (; strip < 256; ++strip) {
            if (cum + part[strip] >= (uint32_t)K_PRE) break;
            cum += part[strip];
        }
        int t1 = 0;
        if (strip < 256) {
            const int top = NB1 - 64 * strip;
            int i = top - 1;
            for (; i >= top - 64; --i) {
                const uint32_t c = gh[i];
                if (cum + c >= (uint32_t)K_PRE) break;
                cum += c;
            }
            if (i < top - 64) i = top - 64;
            t1 = i;
        }
        meta[MT_T1 + b] = (uint32_t)t1;
        meta[MT_CUM + b] = cum;   // count strictly above bucket t1
        meta[MT_CNTC(b)] = 0;     // coarse-stash counter for k_hist2c
    }
}

// Fused: fine histogram of bucket t1 AND coarse candidate stash (u >= t1<<18).
// Each block's slice is 1024 scores -> local stash of 1024 can never overflow.
__global__ __launch_bounds__(256) void k_hist2c(const float4* __restrict__ probs4,
        const uint32_t* __restrict__ meta, uint32_t* cnt_meta,
        uint32_t* __restrict__ hist2, uint64_t* __restrict__ cand_c) {
    __shared__ uint64_t stash[1024];
    __shared__ uint32_t lcnt, lbase;
    const int b = blockIdx.x >> 8;
    const int s = blockIdx.x & 255;
    const uint32_t t1 = meta[MT_T1 + b];
    const uint32_t Tc = t1 << 18;
    if (threadIdx.x == 0) lcnt = 0;
    __syncthreads();
    const float4* p = probs4 + (size_t)b * (NN / 2) + (size_t)s * 512;
    uint32_t* gh = hist2 + (size_t)b * NB2;
    const uint32_t base_n = (uint32_t)s * 1024;
    for (int i = threadIdx.x; i < 512; i += 256) {
        const float4 v = p[i];
        const uint32_t u1 = fkey(v.y);
        const uint32_t u2 = fkey(v.w);
        if ((u1 >> 18) == t1) atomicAdd(&gh[(u1 >> 6) & 0xFFFu], 1u);
        if ((u2 >> 18) == t1) atomicAdd(&gh[(u2 >> 6) & 0xFFFu], 1u);
        if (u1 >= Tc) {
            const uint32_t pos = atomicAdd(&lcnt, 1u);
            stash[pos] = ((uint64_t)u1 << 32) | (uint32_t)(~(base_n + 2u * (uint32_t)i));
        }
        if (u2 >= Tc) {
            const uint32_t pos = atomicAdd(&lcnt, 1u);
            stash[pos] = ((uint64_t)u2 << 32) | (uint32_t)(~(base_n + 2u * (uint32_t)i + 1u));
        }
    }
    __syncthreads();
    if (threadIdx.x == 0) lbase = atomicAdd(&cnt_meta[MT_CNTC(b)], lcnt);
    __syncthreads();
    uint64_t* cc = cand_c + (size_t)b * CANDC_CAP;
    const uint32_t n_loc = lcnt, base = lbase;
    for (uint32_t i = threadIdx.x; i < n_loc; i += 256) {
        const uint32_t pos = base + i;
        if (pos < CANDC_CAP) cc[pos] = stash[i];
    }
}

// Fused: fine-threshold T2 selection + stash filter -> exact candidate set.
__global__ __launch_bounds__(256) void k_thresh2f(const uint32_t* __restrict__ hist2,
        uint32_t* meta, const uint64_t* __restrict__ cand_c, uint64_t* __restrict__ cand) {
    const int b = blockIdx.x;
    const uint32_t* gh = hist2 + (size_t)b * NB2;
    __shared__ uint32_t part[256];
    __shared__ uint32_t sT2, scnt;
    const int t = threadIdx.x;
    uint32_t s = 0;
    const int hi = NB2 - 16 * t;
    for (int i = hi - 16; i < hi; ++i) s += gh[i];
    part[t] = s;
    __syncthreads();
    if (t == 0) {
        const uint32_t t1 = meta[MT_T1 + b];
        uint32_t cum = meta[MT_CUM + b];
        int strip = 0;
        for (; strip < 256; ++strip) {
            if (cum + part[strip] >= (uint32_t)K_PRE) break;
            cum += part[strip];
        }
        int sub = 0;
        if (strip < 256) {
            const int top = NB2 - 16 * strip;
            int i = top - 1;
            for (; i >= top - 16; --i) {
                const uint32_t c = gh[i];
                if (cum + c >= (uint32_t)K_PRE) break;
                cum += c;
            }
            if (i < top - 16) i = top - 16;
            sub = i;
        }
        sT2 = (t1 << 18) | ((uint32_t)sub << 6);
        meta[MT_T2 + b] = sT2;
        meta[MT_KEPT + b] = 0;
        scnt = 0;
    }
    __syncthreads();
    const uint32_t T = sT2;
    const uint32_t mc = min(meta[MT_CNTC(b)], (uint32_t)CANDC_CAP);
    const uint64_t* cc = cand_c + (size_t)b * CANDC_CAP;
    uint64_t* cb = cand + (size_t)b * CAND_CAP;
    for (uint32_t i = (uint32_t)t; i < mc; i += 256) {
        const uint64_t k = cc[i];
        if ((uint32_t)(k >> 32) >= T) {
            const uint32_t pos = atomicAdd(&scnt, 1u);
            if (pos < CAND_CAP) cb[pos] = k;
        }
    }
    __syncthreads();
    if (t == 0) meta[MT_CNT(b)] = scnt;
}

// Rank via monotone binning + suffix scan + within-bin exact compare.
// Exact for any distribution; uniform scores just balance the bins.
__global__ __launch_bounds__(1024) void k_rankonly(const uint64_t* __restrict__ cand,
        const uint32_t* __restrict__ meta, uint32_t* __restrict__ ranks) {
    __shared__ uint64_t skey[CAND_CAP];
    __shared__ uint16_t sbin[CAND_CAP];
    __shared__ uint32_t cnt[RBINS];
    __shared__ uint32_t S[RBINS];
    __shared__ uint16_t order[CAND_CAP];
    __shared__ uint32_t sc[1024];
    const int b = blockIdx.x;
    const int t = threadIdx.x;
    const uint32_t m = min(meta[MT_CNT(b)], (uint32_t)CAND_CAP);
    const uint32_t T2 = meta[MT_T2 + b];
    const uint32_t R = 0xBF800000u - T2;
    const int w = 32 - __clz(R | 1);
    const int sh = (w > 12) ? (w - 12) : 0;
    for (int i = t; i < RBINS; i += 1024) cnt[i] = 0;
    __syncthreads();
    const uint64_t* cb = cand + (size_t)b * CAND_CAP;
    for (uint32_t i = t; i < m; i += 1024) {
        const uint64_t k = cb[i];
        skey[i] = k;
        uint32_t bin = (((uint32_t)(k >> 32)) - T2) >> sh;
        if (bin >= RBINS) bin = RBINS - 1;
        sbin[i] = (uint16_t)bin;
        atomicAdd(&cnt[bin], 1u);
    }
    __syncthreads();
    const uint32_t c1 = cnt[4 * t + 1], c2 = cnt[4 * t + 2], c3 = cnt[4 * t + 3];
    sc[t] = cnt[4 * t] + c1 + c2 + c3;
    __syncthreads();
    for (int d = 1; d < 1024; d <<= 1) {
        const uint32_t v = (t + d < 1024) ? sc[t + d] : 0;
        __syncthreads();
        sc[t] += v;
        __syncthreads();
    }
    const uint32_t Spart = (t + 1 < 1024) ? sc[t + 1] : 0;
    S[4 * t + 3] = Spart;
    S[4 * t + 2] = Spart + c3;
    S[4 * t + 1] = Spart + c3 + c2;
    S[4 * t + 0] = Spart + c3 + c2 + c1;
    __syncthreads();
    for (uint32_t i = t; i < m; i += 1024) {
        const uint32_t bin = sbin[i];
        const uint32_t intra = atomicSub(&cnt[bin], 1u) - 1u;
        order[S[bin] + intra] = (uint16_t)i;
    }
    __syncthreads();
    uint32_t* rb = ranks + (size_t)b * CAND_CAP;
    for (uint32_t i = t; i < m; i += 1024) {
        const uint32_t bin = sbin[i];
        const uint64_t ki = skey[i];
        const uint32_t start = S[bin];
        const uint32_t end = (bin > 0) ? S[bin - 1] : m;
        uint32_t rank = start;
        for (uint32_t s2 = start; s2 < end; ++s2)
            if (skey[order[s2]] > ki) ++rank;
        rb[i] = rank;
    }
}

// Decode gather with full parallelism (256 blocks): random-access reads of
// anch/bbox are HBM-latency-bound and need many waves in flight.
__global__ __launch_bounds__(256) void k_decode(const uint64_t* __restrict__ cand,
        const uint32_t* __restrict__ meta, const uint32_t* __restrict__ ranks,
        const float4* __restrict__ bbox, const float4* __restrict__ anch,
        float4* __restrict__ boxes) {
    const int b = blockIdx.x >> 5;
    const int i = ((blockIdx.x & 31) << 8) + threadIdx.x;
    const uint32_t m = min(meta[MT_CNT(b)], (uint32_t)CAND_CAP);
    if ((uint32_t)i >= m) return;
    const uint32_t rank = ranks[(size_t)b * CAND_CAP + i];
    if (rank >= (uint32_t)K_PRE) return;
    const uint64_t ki = cand[(size_t)b * CAND_CAP + i];
    const uint32_t n = ~((uint32_t)ki);
    const float4 a = anch[(size_t)b * NN + n];
    const float4 d = bbox[(size_t)b * NN + n];
    float h = a.z - a.x, w = a.w - a.y;
    const float cy0 = a.x + 0.5f * h + d.x * 0.1f * h;
    const float cx0 = a.y + 0.5f * w + d.y * 0.1f * w;
    h = h * expf(d.z * 0.2f);
    w = w * expf(d.w * 0.2f);
    float4 o;
    o.x = fminf(fmaxf(cy0 - 0.5f * h, 0.0f), 1.0f);
    o.y = fminf(fmaxf(cx0 - 0.5f * w, 0.0f), 1.0f);
    o.z = fminf(fmaxf(cy0 + 0.5f * h, 0.0f), 1.0f);
    o.w = fminf(fmaxf(cx0 + 0.5f * w, 0.0f), 1.0f);
    boxes[(size_t)b * K_PRE + rank] = o;
}

// IoU bit-matrix, LOWER TRIANGLE tiles only (tj <= ti) — consumers mask
// everything above the diagonal, so upper tiles are never read as data.
__global__ __launch_bounds__(256) void k_matrix(const float4* __restrict__ boxes,
                                                uint32_t* __restrict__ mask) {
    const int b = blockIdx.x / NTILT;
    const int idx = blockIdx.x - b * NTILT;
    int ti = (int)((sqrtf(8.0f * (float)idx + 1.0f) - 1.0f) * 0.5f);
    while ((ti + 1) * (ti + 2) / 2 <= idx) ++ti;
    while (ti * (ti + 1) / 2 > idx) --ti;
    const int tj = idx - ti * (ti + 1) / 2;
    __shared__ float4 rb[64], cb[64];
    __shared__ uint32_t wbits[128];
    const float4* bx = boxes + (size_t)b * K_PRE;
    const int t = threadIdx.x;
    if (t < 64) rb[t] = bx[ti * 64 + t];
    else if (t < 128) cb[t - 64] = bx[tj * 64 + (t - 64)];
    if (t < 128) wbits[t] = 0;
    __syncthreads();
    const int r = t >> 2;
    const int cq = t & 3;
    const float4 a = rb[r];
    const float areaA = (a.z - a.x) * (a.w - a.y);
    uint32_t bits = 0;
#pragma unroll
    for (int jj = 0; jj < 16; ++jj) {
        const float4 cc = cb[cq * 16 + jj];
        const float yy1 = fmaxf(a.x, cc.x), xx1 = fmaxf(a.y, cc.y);
        const float yy2 = fminf(a.z, cc.z), xx2 = fminf(a.w, cc.w);
        const float inter = fmaxf(yy2 - yy1, 0.0f) * fmaxf(xx2 - xx1, 0.0f);
        const float areaC = (cc.z - cc.x) * (cc.w - cc.y);
        const float uni = fmaxf(areaA + areaC - inter, 1e-8f);
        if (inter / uni > NMS_THR) bits |= (1u << jj);
    }
    atomicOr(&wbits[r * 2 + (cq >> 1)], bits << ((cq & 1) * 16));
    __syncthreads();
    if (t < 128) {
        const int rr = t >> 1, ww = t & 1;
        mask[((size_t)b * PREFIX + ti * 64 + rr) * 64 + tj * 2 + ww] = wbits[rr * 2 + ww];
    }
}

// Conflict extraction (lower triangle only; words > iw masked).
__global__ __launch_bounds__(256) void k_conflict(const uint32_t* __restrict__ mask,
        uint64_t* __restrict__ sinfo, uint32_t* __restrict__ cbm) {
    const int b = blockIdx.x >> 3;
    const int s = blockIdx.x & 7;
    const int i = (s << 8) + threadIdx.x;
    const uint4* row4 = (const uint4*)(mask + ((size_t)b * PREFIX + i) * 64);
    const int iw = i >> 5;
    const uint32_t tailmask = ((uint32_t)1 << (i & 31)) - 1u;
    uint32_t cnt = 0;
    uint64_t packed = 0;
    for (int c = 0; c <= (iw >> 2); ++c) {
        const uint4 q = row4[c];
        uint32_t ws[4] = {q.x, q.y, q.z, q.w};
#pragma unroll
        for (int k = 0; k < 4; ++k) {
            const int w = c * 4 + k;
            uint32_t bits = ws[k];
            if (w > iw) bits = 0;
            else if (w == iw) bits &= tailmask;
            while (bits) {
                const int bp = __ffs(bits) - 1;
                bits &= bits - 1;
                if (cnt < 5) packed |= (uint64_t)(uint32_t)(w * 32 + bp) << (12 * cnt);
                ++cnt;
            }
        }
    }
    packed |= (uint64_t)(cnt <= 5 ? cnt : 6) << 60;   // 6 = heavy (rescan row)
    sinfo[(size_t)b * PREFIX + i] = packed;
    const unsigned long long bm = __ballot(cnt != 0);
    const int wv = threadIdx.x >> 6;
    const int lid = threadIdx.x & 63;
    if (lid == 0) cbm[(size_t)b * 64 + (s << 3) + wv * 2] = (uint32_t)bm;
    else if (lid == 1) cbm[(size_t)b * 64 + (s << 3) + wv * 2 + 1] = (uint32_t)(bm >> 32);
}

// Greedy resolution: taken-bitmap in lane registers; only conflicted rows
// (~3%) resolved serially ascending; emit first min(1000,total) taken rows.
__global__ __launch_bounds__(64) void k_greedy(const uint32_t* __restrict__ mask,
        const uint64_t* __restrict__ sinfo, const uint32_t* __restrict__ cbm,
        uint32_t* meta, uint32_t* __restrict__ kept_idx) {
    __shared__ uint32_t conf_rows[PREFIX];
    __shared__ uint32_t ncf_s;
    const int b = blockIdx.x;
    const int lane = threadIdx.x;
    const uint32_t cw = cbm[(size_t)b * 64 + lane];
    uint32_t taken = 0xFFFFFFFFu;

    const uint32_t pc = (uint32_t)__popc(cw);
    uint32_t pref = pc;
    for (int d = 1; d < 64; d <<= 1) {
        const uint32_t v = __shfl_up(pref, d);
        if (lane >= d) pref += v;
    }
    const uint32_t ncf = __shfl(pref, 63);
    uint32_t idx = pref - pc;
    uint32_t tm = cw;
    while (tm) {
        const int q = __ffs(tm) - 1;
        tm &= tm - 1;
        conf_rows[idx] = (uint32_t)(lane * 32 + q);
        ++idx;
    }
    if (lane == 0) ncf_s = ncf;
    __syncthreads();

    uint32_t r_i[4], r_lo[4], r_hi[4];
#pragma unroll
    for (int r = 0; r < 4; ++r) {
        const uint32_t k = (uint32_t)(r * 64 + lane);
        const uint32_t ri = (k < ncf) ? conf_rows[k] : 0;
        const uint64_t nf = (k < ncf) ? sinfo[(size_t)b * PREFIX + ri] : 0ull;
        r_i[r] = ri;
        r_lo[r] = (uint32_t)nf;
        r_hi[r] = (uint32_t)(nf >> 32);
    }

    const uint32_t* mbase = mask + (size_t)b * PREFIX * 64;

#pragma unroll
    for (int seg = 0; seg < 4; ++seg) {
        const uint32_t segbase = (uint32_t)(seg * 64);
        if (segbase < ncf) {
            const uint32_t segcnt = min(64u, ncf - segbase);
            for (uint32_t k2 = 0; k2 < segcnt; ++k2) {
                const uint32_t i  = __builtin_amdgcn_readlane(r_i[seg], (int)k2);
                const uint32_t lo = __builtin_amdgcn_readlane(r_lo[seg], (int)k2);
                const uint32_t hi = __builtin_amdgcn_readlane(r_hi[seg], (int)k2);
                const uint32_t cnt = hi >> 28;
                bool dropped = false;
                if (cnt == 6) {
                    const uint32_t* row = mbase + (size_t)i * 64;
                    const int iw = i >> 5;
                    for (int w = 0; w <= iw; ++w) {
                        uint32_t bits = row[w];
                        if (w == iw) bits &= (((uint32_t)1 << (i & 31)) - 1u);
                        const uint32_t tk = __builtin_amdgcn_readlane(taken, w);
                        if (bits & tk) { dropped = true; break; }
                    }
                } else {
                    uint64_t p = ((uint64_t)hi << 32) | lo;
                    for (uint32_t c = 0; c < cnt; ++c) {
                        const uint32_t j = (uint32_t)(p & 0xFFFu);
                        p >>= 12;
                        const uint32_t tk = __builtin_amdgcn_readlane(taken, (int)(j >> 5));
                        if ((tk >> (j & 31)) & 1u) dropped = true;
                    }
                }
                if (dropped) {
                    const int w = (int)(i >> 5);
                    if (lane == w) taken &= ~((uint32_t)1 << (i & 31));
                }
            }
        }
    }
    for (uint32_t k = 256; k < ncf; ++k) {
        const uint32_t i = conf_rows[k];
        const uint64_t nf = sinfo[(size_t)b * PREFIX + i];
        const uint32_t cnt = (uint32_t)(nf >> 60);
        bool dropped = false;
        if (cnt == 6) {
            const uint32_t* row = mbase + (size_t)i * 64;
            const int iw = i >> 5;
            for (int w = 0; w <= iw; ++w) {
                uint32_t bits = row[w];
                if (w == iw) bits &= (((uint32_t)1 << (i & 31)) - 1u);
                const uint32_t tk = __builtin_amdgcn_readlane(taken, w);
                if (bits & tk) { dropped = true; break; }
            }
        } else {
            uint64_t p = nf;
            for (uint32_t c = 0; c < cnt; ++c) {
                const uint32_t j = (uint32_t)(p & 0xFFFu);
                p >>= 12;
                const uint32_t tk = __builtin_amdgcn_readlane(taken, (int)(j >> 5));
                if ((tk >> (j & 31)) & 1u) dropped = true;
            }
        }
        if (dropped) {
            const int w = (int)(i >> 5);
            if (lane == w) taken &= ~((uint32_t)1 << (i & 31));
        }
    }

    const uint32_t tpc = (uint32_t)__popc(taken);
    uint32_t tpref = tpc;
    for (int d = 1; d < 64; d <<= 1) {
        const uint32_t v = __shfl_up(tpref, d);
        if (lane >= d) tpref += v;
    }
    const uint32_t total = __shfl(tpref, 63);
    uint32_t rank = tpref - tpc;
    uint32_t w = taken;
    while (w) {
        const int q = __ffs(w) - 1;
        w &= w - 1;
        if (rank < (uint32_t)NPROP)
            kept_idx[(size_t)b * NPROP + rank] = (uint32_t)(lane * 32 + q);
        ++rank;
    }
    if (lane == 0) meta[MT_KEPT + b] = min(total, (uint32_t)NPROP);
}

__global__ __launch_bounds__(1024) void k_finish(const float4* __restrict__ boxes,
        uint32_t* meta, uint32_t* kept_idx, float4* __restrict__ out) {
    const int b = blockIdx.x;
    const float4* bx = boxes + (size_t)b * K_PRE;
    __shared__ float4 kb[NPROP];
    __shared__ uint32_t sflag;
    uint32_t kept = meta[MT_KEPT + b];
    if (kept < NPROP) {
        for (uint32_t k = threadIdx.x; k < kept; k += 1024)
            kb[k] = bx[kept_idx[(size_t)b * NPROP + k]];
        __syncthreads();
        for (int i = PREFIX; i < K_PRE && kept < NPROP; ++i) {
            if (threadIdx.x == 0) sflag = 0;
            __syncthreads();
            const float4 c = bx[i];
            const float areaC = (c.z - c.x) * (c.w - c.y);
            bool sup = false;
            for (uint32_t k = threadIdx.x; k < kept; k += 1024) {
                const float4 a = kb[k];
                const float yy1 = fmaxf(c.x, a.x), xx1 = fmaxf(c.y, a.y);
                const float yy2 = fminf(c.z, a.z), xx2 = fminf(c.w, a.w);
                const float inter = fmaxf(yy2 - yy1, 0.0f) * fmaxf(xx2 - xx1, 0.0f);
                const float areaA = (a.z - a.x) * (a.w - a.y);
                const float uni = fmaxf(areaC + areaA - inter, 1e-8f);
                if (inter / uni > NMS_THR) { sup = true; break; }
            }
            if (sup) atomicOr(&sflag, 1u);
            __syncthreads();
            if (sflag == 0) {
                if (threadIdx.x == 0) {
                    kept_idx[(size_t)b * NPROP + kept] = (uint32_t)i;
                    kb[kept] = c;
                }
                ++kept;
            }
            __syncthreads();
        }
        if (threadIdx.x == 0) meta[MT_KEPT + b] = kept;
    }
    __syncthreads();
    for (uint32_t k = threadIdx.x; k < NPROP; k += 1024) {
        float4 v = make_float4(0.f, 0.f, 0.f, 0.f);
        if (k < kept) v = bx[kept_idx[(size_t)b * NPROP + k]];
        out[(size_t)b * NPROP + k] = v;
    }
}

extern "C" void kernel_launch(void* const* d_in, const int* in_sizes, int n_in,
                              void* d_out, int out_size, void* d_ws, size_t ws_size,
                              hipStream_t stream) {
    const float4* probs4 = (const float4*)d_in[0];
    const float4* bbox   = (const float4*)d_in[1];
    const float4* anch   = (const float4*)d_in[2];
    char* ws = (char*)d_ws;
    if (ws_size < (size_t)WS_NEED) return;
    uint32_t* hist1 = (uint32_t*)(ws + HIST1_OFF);
    uint32_t* hist2 = (uint32_t*)(ws + HIST2_OFF);
    uint32_t* meta  = (uint32_t*)(ws + META_OFF);
    uint64_t* cand  = (uint64_t*)(ws + CAND_OFF);
    float4*   boxes = (float4*)(ws + BOXES_OFF);
    uint32_t* mask  = (uint32_t*)(ws + MASK_OFF);
    uint32_t* kidx  = (uint32_t*)(ws + KIDX_OFF);
    uint64_t* candc = (uint64_t*)(ws + CANDC_OFF);
    uint64_t* sinfo = (uint64_t*)(ws + HIST1_OFF);   // reuse: hist1 dead after k_thresh
    uint32_t* cbm   = (uint32_t*)(ws + HIST2_OFF);   // reuse: hist2 dead after k_thresh2f
    uint32_t* ranks = (uint32_t*)(ws + CANDC_OFF);   // reuse: candc dead after k_thresh2f

    k_zero<<<dim3((HZERO + 255) / 256), dim3(256), 0, stream>>>(hist1);
    k_hist<<<dim3(512), dim3(256), 0, stream>>>(probs4, hist1);
    k_thresh<<<dim3(BATCH), dim3(256), 0, stream>>>(hist1, meta);
    k_hist2c<<<dim3(2048), dim3(256), 0, stream>>>(probs4, meta, meta, hist2, candc);
    k_thresh2f<<<dim3(BATCH), dim3(256), 0, stream>>>(hist2, meta, candc, cand);
    k_rankonly<<<dim3(BATCH), dim3(1024), 0, stream>>>(cand, meta, ranks);
    k_decode<<<dim3(BATCH * 32), dim3(256), 0, stream>>>(cand, meta, ranks, bbox, anch, boxes);
    k_matrix<<<dim3(BATCH * NTILT), dim3(256), 0, stream>>>(boxes, mask);
    k_conflict<<<dim3(BATCH * 8), dim3(256), 0, stream>>>(mask, sinfo, cbm);
    k_greedy<<<dim3(BATCH), dim3(64), 0, stream>>>(mask, sinfo, cbm, meta, kidx);
    k_finish<<<dim3(BATCH), dim3(1024), 0, stream>>>(boxes, meta, kidx, (float4*)d_out);
}

// Round 18
// 109.595 us; speedup vs baseline: 1.4427x; 1.0002x over previous
//
#include <hip/hip_runtime.h>
#include <stdint.h>

#define BATCH 8
#define NN 262144
#define K_PRE 6000
#define NPROP 1000
#define NMS_THR 0.7f
#define CAND_CAP 8192
#define CANDC_CAP 16384
#define PREFIX 2048
#define NB1 16384
#define NB2 4096
#define RBINS 4096
#define NTILT 528      // lower-triangle tiles: 32*33/2

// meta u32 indices
#define MT_T2 0        // [0..7]   final threshold
#define MT_KEPT 16     // [16..23] kept count
#define MT_CNT(b)   (64 + 32*(b))       // exact candidate count
#define MT_CNTC(b)  (64 + 32*(b) + 16)  // coarse-stash count

// workspace layout (bytes)
#define HIST1_OFF 0                                   // BATCH*NB1*4 = 524288
#define HIST2_OFF (HIST1_OFF + BATCH*NB1*4)           // + BATCH*NB2*4 = 131072
#define META_OFF  (HIST2_OFF + BATCH*NB2*4)           // 2048 B
#define CAND_OFF  (META_OFF + 2048)
#define BOXES_OFF (CAND_OFF + BATCH*CAND_CAP*8)       // BATCH*K_PRE*16
#define MASK_OFF  (BOXES_OFF + BATCH*K_PRE*16)        // BATCH*PREFIX*64*4 = 4 MB
#define KIDX_OFF  (MASK_OFF + (size_t)BATCH*PREFIX*64*4)
#define CANDC_OFF (KIDX_OFF + BATCH*NPROP*4)          // BATCH*CANDC_CAP*8 = 1 MB
#define WS_NEED   (CANDC_OFF + (size_t)BATCH*CANDC_CAP*8)

// region reuse (lifetimes disjoint, all deps stream-ordered):
//  - ranks (u32[BATCH*CAND_CAP] = 256KB) -> MASK region (dead until k_matrix;
//    written by k_rankfd, read by k_decode, then k_matrix overwrites)
//  - sinfo (u64[BATCH*PREFIX] = 128KB)   -> HIST1 region (dead after k_rankfd)
//  - cbm (u32[BATCH*64] = 2KB)           -> HIST2 region (dead after k_rankfd)

#define HZERO (BATCH * (NB1 + NB2))                   // u32s of histograms

__device__ __forceinline__ uint32_t fkey(float f) {
    uint32_t b = __float_as_uint(f);
    return b ^ (uint32_t)(((int32_t)b >> 31) | 0x80000000u);
}

__global__ void k_zero(uint32_t* h, uint32_t* meta) {
    const int i = blockIdx.x * 256 + threadIdx.x;
    if (i < HZERO) h[i] = 0;
    if (blockIdx.x == 0 && threadIdx.x < BATCH) meta[MT_CNTC(threadIdx.x)] = 0;
}

// 512 blocks = 64 per batch; each block: 2048 float4 (= 4096 elements).
__global__ __launch_bounds__(256) void k_hist(const float4* __restrict__ probs4,
                                              uint32_t* __restrict__ hist) {
    __shared__ uint32_t h[NB1];
    for (int i = threadIdx.x; i < NB1; i += 256) h[i] = 0;
    __syncthreads();
    const int b = blockIdx.x >> 6;
    const int s = blockIdx.x & 63;
    const float4* p = probs4 + (size_t)b * (NN / 2) + (size_t)s * 2048;
    for (int i = threadIdx.x; i < 2048; i += 256) {
        const float4 v = p[i];
        atomicAdd(&h[fkey(v.y) >> 18], 1u);
        atomicAdd(&h[fkey(v.w) >> 18], 1u);
    }
    __syncthreads();
    uint32_t* gh = hist + (size_t)b * NB1;
    for (int i = threadIdx.x; i < NB1; i += 256)
        if (h[i]) atomicAdd(&gh[i], h[i]);
}

// Parallel descending radix-select over hist1 (exact same semantics as the
// old serial k_thresh): strip sums -> inclusive scan -> crossing strip ->
// wave-prefix refine within the strip. Each k_hist2c block recomputes t1
// locally (hist1 is L2-hot) -- kills the tiny serializing k_thresh dispatch.
__global__ __launch_bounds__(256) void k_hist2c(const float4* __restrict__ probs4,
        const uint32_t* __restrict__ hist1, uint32_t* cnt_meta,
        uint32_t* __restrict__ hist2, uint64_t* __restrict__ cand_c) {
    __shared__ uint32_t part[256], orig[256];
    __shared__ uint32_t l_strip, l_cumb, l_t1;
    __shared__ uint64_t stash[1024];
    __shared__ uint32_t lcnt, lbase;
    const int b = blockIdx.x >> 8;
    const int s = blockIdx.x & 255;
    const int t = threadIdx.x;
    const uint32_t* gh1 = hist1 + (size_t)b * NB1;
    // strip sums (strip t = bins [NB1-64(t+1), NB1-64t), descending order)
    {
        uint32_t sum = 0;
        const int hi = NB1 - 64 * t;
        for (int i = hi - 64; i < hi; ++i) sum += gh1[i];
        orig[t] = sum; part[t] = sum;
    }
    if (t == 0) lcnt = 0;
    __syncthreads();
    for (int d = 1; d < 256; d <<= 1) {
        const uint32_t v = (t >= d) ? part[t - d] : 0;
        __syncthreads();
        part[t] += v;
        __syncthreads();
    }
    {
        const uint32_t incl = part[t], cumb = incl - orig[t];
        if (incl >= (uint32_t)K_PRE && cumb < (uint32_t)K_PRE) { l_strip = t; l_cumb = cumb; }
    }
    __syncthreads();
    if (t < 64) {
        const int top = NB1 - 64 * (int)l_strip;
        const uint32_t c = gh1[top - 1 - t];
        uint32_t p = c;
        for (int d = 1; d < 64; d <<= 1) {
            const uint32_t v = __shfl_up(p, d);
            if (t >= d) p += v;
        }
        const uint32_t tot = l_cumb + p;
        if (tot >= (uint32_t)K_PRE && tot - c < (uint32_t)K_PRE)
            l_t1 = (uint32_t)(top - 1 - t);
    }
    __syncthreads();
    const uint32_t t1 = l_t1;
    const uint32_t Tc = t1 << 18;
    // fine histogram of bucket t1 + coarse stash (u >= Tc); slice = 1024
    // scores -> local stash of 1024 can never overflow.
    const float4* p = probs4 + (size_t)b * (NN / 2) + (size_t)s * 512;
    uint32_t* gh = hist2 + (size_t)b * NB2;
    const uint32_t base_n = (uint32_t)s * 1024;
    for (int i = t; i < 512; i += 256) {
        const float4 v = p[i];
        const uint32_t u1 = fkey(v.y);
        const uint32_t u2 = fkey(v.w);
        if ((u1 >> 18) == t1) atomicAdd(&gh[(u1 >> 6) & 0xFFFu], 1u);
        if ((u2 >> 18) == t1) atomicAdd(&gh[(u2 >> 6) & 0xFFFu], 1u);
        if (u1 >= Tc) {
            const uint32_t pos = atomicAdd(&lcnt, 1u);
            stash[pos] = ((uint64_t)u1 << 32) | (uint32_t)(~(base_n + 2u * (uint32_t)i));
        }
        if (u2 >= Tc) {
            const uint32_t pos = atomicAdd(&lcnt, 1u);
            stash[pos] = ((uint64_t)u2 << 32) | (uint32_t)(~(base_n + 2u * (uint32_t)i + 1u));
        }
    }
    __syncthreads();
    if (t == 0) lbase = atomicAdd(&cnt_meta[MT_CNTC(b)], lcnt);
    __syncthreads();
    uint64_t* cc = cand_c + (size_t)b * CANDC_CAP;
    const uint32_t n_loc = lcnt, base = lbase;
    for (uint32_t i = (uint32_t)t; i < n_loc; i += 256) {
        const uint32_t pos = base + i;
        if (pos < CANDC_CAP) cc[pos] = stash[i];
    }
}

// Fused: T2 selection (t1,cum from hist1; sub from hist2) + stash filter +
// compacted cand write + binning ranks. One block per batch.
__global__ __launch_bounds__(1024) void k_rankfd(const uint32_t* __restrict__ hist1,
        const uint32_t* __restrict__ hist2, uint32_t* meta,
        const uint64_t* __restrict__ cand_c, uint64_t* __restrict__ cand,
        uint32_t* __restrict__ ranks) {
    __shared__ uint64_t skey[CAND_CAP];     // 64 KB
    __shared__ uint16_t sbin[CAND_CAP];     // 16 KB
    __shared__ uint32_t cnt[RBINS];         // 16 KB
    __shared__ uint32_t S[RBINS];           // 16 KB
    __shared__ uint16_t order[CAND_CAP];    // 16 KB
    __shared__ uint32_t sc[1024];           // 4 KB
    __shared__ uint32_t part[256], orig[256];
    __shared__ uint32_t l_strip, l_cumb, l_t1, l_cum, l_T2, l_m;
    const int b = blockIdx.x;
    const int t = threadIdx.x;
    const uint32_t* gh1 = hist1 + (size_t)b * NB1;
    const uint32_t* gh2 = hist2 + (size_t)b * NB2;

    // ---- phase 1: t1 & cum from hist1 ----
    if (t < 256) {
        uint32_t sum = 0;
        const int hi = NB1 - 64 * t;
        for (int i = hi - 64; i < hi; ++i) sum += gh1[i];
        orig[t] = sum; part[t] = sum;
    }
    __syncthreads();
    for (int d = 1; d < 256; d <<= 1) {
        uint32_t v = 0;
        if (t < 256 && t >= d) v = part[t - d];
        __syncthreads();
        if (t < 256) part[t] += v;
        __syncthreads();
    }
    if (t < 256) {
        const uint32_t incl = part[t], cumb = incl - orig[t];
        if (incl >= (uint32_t)K_PRE && cumb < (uint32_t)K_PRE) { l_strip = t; l_cumb = cumb; }
    }
    __syncthreads();
    if (t < 64) {
        const int top = NB1 - 64 * (int)l_strip;
        const uint32_t c = gh1[top - 1 - t];
        uint32_t p = c;
        for (int d = 1; d < 64; d <<= 1) {
            const uint32_t v = __shfl_up(p, d);
            if (t >= d) p += v;
        }
        const uint32_t tot = l_cumb + p;
        if (tot >= (uint32_t)K_PRE && tot - c < (uint32_t)K_PRE) {
            l_t1 = (uint32_t)(top - 1 - t);
            l_cum = tot - c;
        }
    }
    __syncthreads();
    const uint32_t t1 = l_t1, cum = l_cum;

    // ---- phase 2: T2 (sub-bucket) from hist2, offset by cum ----
    if (t < 256) {
        uint32_t sum = 0;
        const int hi = NB2 - 16 * t;
        for (int i = hi - 16; i < hi; ++i) sum += gh2[i];
        orig[t] = sum; part[t] = sum;
    }
    __syncthreads();
    for (int d = 1; d < 256; d <<= 1) {
        uint32_t v = 0;
        if (t < 256 && t >= d) v = part[t - d];
        __syncthreads();
        if (t < 256) part[t] += v;
        __syncthreads();
    }
    if (t < 256) {
        const uint32_t incl = cum + part[t], cumb = incl - orig[t];
        if (incl >= (uint32_t)K_PRE && cumb < (uint32_t)K_PRE) { l_strip = t; l_cumb = cumb; }
    }
    __syncthreads();
    if (t < 16) {
        const int top = NB2 - 16 * (int)l_strip;
        const uint32_t c = gh2[top - 1 - t];
        uint32_t p = c;
        for (int d = 1; d < 16; d <<= 1) {
            const uint32_t v = __shfl_up(p, d);
            if (t >= d) p += v;
        }
        const uint32_t tot = l_cumb + p;
        if (tot >= (uint32_t)K_PRE && tot - c < (uint32_t)K_PRE)
            l_T2 = (t1 << 18) | ((uint32_t)(top - 1 - t) << 6);
    }
    if (t == 0) l_m = 0;
    __syncthreads();
    const uint32_t T2 = l_T2;

    // ---- filter coarse stash by exact T2 into LDS ----
    const uint32_t mc = min(meta[MT_CNTC(b)], (uint32_t)CANDC_CAP);
    const uint64_t* cc = cand_c + (size_t)b * CANDC_CAP;
    for (uint32_t i = (uint32_t)t; i < mc; i += 1024) {
        const uint64_t k = cc[i];
        if ((uint32_t)(k >> 32) >= T2) {
            const uint32_t pos = atomicAdd(&l_m, 1u);
            if (pos < CAND_CAP) skey[pos] = k;
        }
    }
    __syncthreads();
    const uint32_t m = min(l_m, (uint32_t)CAND_CAP);
    if (t == 0) { meta[MT_CNT(b)] = m; meta[MT_T2 + b] = T2; }
    uint64_t* cb = cand + (size_t)b * CAND_CAP;
    for (uint32_t i = (uint32_t)t; i < m; i += 1024) cb[i] = skey[i];

    // ---- binning + suffix scan + within-bin exact rank ----
    const uint32_t R = 0xBF800000u - T2;
    const int w = 32 - __clz(R | 1);
    const int sh = (w > 12) ? (w - 12) : 0;
    for (int i = t; i < RBINS; i += 1024) cnt[i] = 0;
    __syncthreads();
    for (uint32_t i = (uint32_t)t; i < m; i += 1024) {
        uint32_t bin = (((uint32_t)(skey[i] >> 32)) - T2) >> sh;
        if (bin >= RBINS) bin = RBINS - 1;
        sbin[i] = (uint16_t)bin;
        atomicAdd(&cnt[bin], 1u);
    }
    __syncthreads();
    const uint32_t c1 = cnt[4 * t + 1], c2 = cnt[4 * t + 2], c3 = cnt[4 * t + 3];
    sc[t] = cnt[4 * t] + c1 + c2 + c3;
    __syncthreads();
    for (int d = 1; d < 1024; d <<= 1) {
        const uint32_t v = (t + d < 1024) ? sc[t + d] : 0;
        __syncthreads();
        sc[t] += v;
        __syncthreads();
    }
    const uint32_t Spart = (t + 1 < 1024) ? sc[t + 1] : 0;
    S[4 * t + 3] = Spart;
    S[4 * t + 2] = Spart + c3;
    S[4 * t + 1] = Spart + c3 + c2;
    S[4 * t + 0] = Spart + c3 + c2 + c1;
    __syncthreads();
    for (uint32_t i = (uint32_t)t; i < m; i += 1024) {
        const uint32_t bin = sbin[i];
        const uint32_t intra = atomicSub(&cnt[bin], 1u) - 1u;
        order[S[bin] + intra] = (uint16_t)i;
    }
    __syncthreads();
    uint32_t* rb = ranks + (size_t)b * CAND_CAP;
    for (uint32_t i = (uint32_t)t; i < m; i += 1024) {
        const uint32_t bin = sbin[i];
        const uint64_t ki = skey[i];
        const uint32_t start = S[bin];
        const uint32_t end = (bin > 0) ? S[bin - 1] : m;
        uint32_t rank = start;
        for (uint32_t s2 = start; s2 < end; ++s2)
            if (skey[order[s2]] > ki) ++rank;
        rb[i] = rank;
    }
}

// Decode gather with full parallelism (256 blocks): random-access reads of
// anch/bbox are HBM-latency-bound and need many waves in flight.
__global__ __launch_bounds__(256) void k_decode(const uint64_t* __restrict__ cand,
        const uint32_t* __restrict__ meta, const uint32_t* __restrict__ ranks,
        const float4* __restrict__ bbox, const float4* __restrict__ anch,
        float4* __restrict__ boxes) {
    const int b = blockIdx.x >> 5;
    const int i = ((blockIdx.x & 31) << 8) + threadIdx.x;
    const uint32_t m = min(meta[MT_CNT(b)], (uint32_t)CAND_CAP);
    if ((uint32_t)i >= m) return;
    const uint32_t rank = ranks[(size_t)b * CAND_CAP + i];
    if (rank >= (uint32_t)K_PRE) return;
    const uint64_t ki = cand[(size_t)b * CAND_CAP + i];
    const uint32_t n = ~((uint32_t)ki);
    const float4 a = anch[(size_t)b * NN + n];
    const float4 d = bbox[(size_t)b * NN + n];
    float h = a.z - a.x, w = a.w - a.y;
    const float cy0 = a.x + 0.5f * h + d.x * 0.1f * h;
    const float cx0 = a.y + 0.5f * w + d.y * 0.1f * w;
    h = h * expf(d.z * 0.2f);
    w = w * expf(d.w * 0.2f);
    float4 o;
    o.x = fminf(fmaxf(cy0 - 0.5f * h, 0.0f), 1.0f);
    o.y = fminf(fmaxf(cx0 - 0.5f * w, 0.0f), 1.0f);
    o.z = fminf(fmaxf(cy0 + 0.5f * h, 0.0f), 1.0f);
    o.w = fminf(fmaxf(cx0 + 0.5f * w, 0.0f), 1.0f);
    boxes[(size_t)b * K_PRE + rank] = o;
}

// IoU bit-matrix, LOWER TRIANGLE tiles only (tj <= ti).
__global__ __launch_bounds__(256) void k_matrix(const float4* __restrict__ boxes,
                                                uint32_t* __restrict__ mask) {
    const int b = blockIdx.x / NTILT;
    const int idx = blockIdx.x - b * NTILT;
    int ti = (int)((sqrtf(8.0f * (float)idx + 1.0f) - 1.0f) * 0.5f);
    while ((ti + 1) * (ti + 2) / 2 <= idx) ++ti;
    while (ti * (ti + 1) / 2 > idx) --ti;
    const int tj = idx - ti * (ti + 1) / 2;
    __shared__ float4 rb[64], cb[64];
    __shared__ uint32_t wbits[128];
    const float4* bx = boxes + (size_t)b * K_PRE;
    const int t = threadIdx.x;
    if (t < 64) rb[t] = bx[ti * 64 + t];
    else if (t < 128) cb[t - 64] = bx[tj * 64 + (t - 64)];
    if (t < 128) wbits[t] = 0;
    __syncthreads();
    const int r = t >> 2;
    const int cq = t & 3;
    const float4 a = rb[r];
    const float areaA = (a.z - a.x) * (a.w - a.y);
    uint32_t bits = 0;
#pragma unroll
    for (int jj = 0; jj < 16; ++jj) {
        const float4 cc = cb[cq * 16 + jj];
        const float yy1 = fmaxf(a.x, cc.x), xx1 = fmaxf(a.y, cc.y);
        const float yy2 = fminf(a.z, cc.z), xx2 = fminf(a.w, cc.w);
        const float inter = fmaxf(yy2 - yy1, 0.0f) * fmaxf(xx2 - xx1, 0.0f);
        const float areaC = (cc.z - cc.x) * (cc.w - cc.y);
        const float uni = fmaxf(areaA + areaC - inter, 1e-8f);
        if (inter / uni > NMS_THR) bits |= (1u << jj);
    }
    atomicOr(&wbits[r * 2 + (cq >> 1)], bits << ((cq & 1) * 16));
    __syncthreads();
    if (t < 128) {
        const int rr = t >> 1, ww = t & 1;
        mask[((size_t)b * PREFIX + ti * 64 + rr) * 64 + tj * 2 + ww] = wbits[rr * 2 + ww];
    }
}

// Conflict extraction (lower triangle only; words > iw masked).
__global__ __launch_bounds__(256) void k_conflict(const uint32_t* __restrict__ mask,
        uint64_t* __restrict__ sinfo, uint32_t* __restrict__ cbm) {
    const int b = blockIdx.x >> 3;
    const int s = blockIdx.x & 7;
    const int i = (s << 8) + threadIdx.x;
    const uint4* row4 = (const uint4*)(mask + ((size_t)b * PREFIX + i) * 64);
    const int iw = i >> 5;
    const uint32_t tailmask = ((uint32_t)1 << (i & 31)) - 1u;
    uint32_t cnt = 0;
    uint64_t packed = 0;
    for (int c = 0; c <= (iw >> 2); ++c) {
        const uint4 q = row4[c];
        uint32_t ws[4] = {q.x, q.y, q.z, q.w};
#pragma unroll
        for (int k = 0; k < 4; ++k) {
            const int w = c * 4 + k;
            uint32_t bits = ws[k];
            if (w > iw) bits = 0;
            else if (w == iw) bits &= tailmask;
            while (bits) {
                const int bp = __ffs(bits) - 1;
                bits &= bits - 1;
                if (cnt < 5) packed |= (uint64_t)(uint32_t)(w * 32 + bp) << (12 * cnt);
                ++cnt;
            }
        }
    }
    packed |= (uint64_t)(cnt <= 5 ? cnt : 6) << 60;   // 6 = heavy (rescan row)
    sinfo[(size_t)b * PREFIX + i] = packed;
    const unsigned long long bm = __ballot(cnt != 0);
    const int wv = threadIdx.x >> 6;
    const int lid = threadIdx.x & 63;
    if (lid == 0) cbm[(size_t)b * 64 + (s << 3) + wv * 2] = (uint32_t)bm;
    else if (lid == 1) cbm[(size_t)b * 64 + (s << 3) + wv * 2 + 1] = (uint32_t)(bm >> 32);
}

// Greedy resolution: taken-bitmap in lane registers; only conflicted rows
// (~3%) resolved serially ascending; emit first min(1000,total) taken rows.
__global__ __launch_bounds__(64) void k_greedy(const uint32_t* __restrict__ mask,
        const uint64_t* __restrict__ sinfo, const uint32_t* __restrict__ cbm,
        uint32_t* meta, uint32_t* __restrict__ kept_idx) {
    __shared__ uint32_t conf_rows[PREFIX];
    __shared__ uint32_t ncf_s;
    const int b = blockIdx.x;
    const int lane = threadIdx.x;
    const uint32_t cw = cbm[(size_t)b * 64 + lane];
    uint32_t taken = 0xFFFFFFFFu;

    const uint32_t pc = (uint32_t)__popc(cw);
    uint32_t pref = pc;
    for (int d = 1; d < 64; d <<= 1) {
        const uint32_t v = __shfl_up(pref, d);
        if (lane >= d) pref += v;
    }
    const uint32_t ncf = __shfl(pref, 63);
    uint32_t idx = pref - pc;
    uint32_t tm = cw;
    while (tm) {
        const int q = __ffs(tm) - 1;
        tm &= tm - 1;
        conf_rows[idx] = (uint32_t)(lane * 32 + q);
        ++idx;
    }
    if (lane == 0) ncf_s = ncf;
    __syncthreads();

    uint32_t r_i[4], r_lo[4], r_hi[4];
#pragma unroll
    for (int r = 0; r < 4; ++r) {
        const uint32_t k = (uint32_t)(r * 64 + lane);
        const uint32_t ri = (k < ncf) ? conf_rows[k] : 0;
        const uint64_t nf = (k < ncf) ? sinfo[(size_t)b * PREFIX + ri] : 0ull;
        r_i[r] = ri;
        r_lo[r] = (uint32_t)nf;
        r_hi[r] = (uint32_t)(nf >> 32);
    }

    const uint32_t* mbase = mask + (size_t)b * PREFIX * 64;

#pragma unroll
    for (int seg = 0; seg < 4; ++seg) {
        const uint32_t segbase = (uint32_t)(seg * 64);
        if (segbase < ncf) {
            const uint32_t segcnt = min(64u, ncf - segbase);
            for (uint32_t k2 = 0; k2 < segcnt; ++k2) {
                const uint32_t i  = __builtin_amdgcn_readlane(r_i[seg], (int)k2);
                const uint32_t lo = __builtin_amdgcn_readlane(r_lo[seg], (int)k2);
                const uint32_t hi = __builtin_amdgcn_readlane(r_hi[seg], (int)k2);
                const uint32_t cnt = hi >> 28;
                bool dropped = false;
                if (cnt == 6) {
                    const uint32_t* row = mbase + (size_t)i * 64;
                    const int iw = i >> 5;
                    for (int w = 0; w <= iw; ++w) {
                        uint32_t bits = row[w];
                        if (w == iw) bits &= (((uint32_t)1 << (i & 31)) - 1u);
                        const uint32_t tk = __builtin_amdgcn_readlane(taken, w);
                        if (bits & tk) { dropped = true; break; }
                    }
                } else {
                    uint64_t p = ((uint64_t)hi << 32) | lo;
                    for (uint32_t c = 0; c < cnt; ++c) {
                        const uint32_t j = (uint32_t)(p & 0xFFFu);
                        p >>= 12;
                        const uint32_t tk = __builtin_amdgcn_readlane(taken, (int)(j >> 5));
                        if ((tk >> (j & 31)) & 1u) dropped = true;
                    }
                }
                if (dropped) {
                    const int w = (int)(i >> 5);
                    if (lane == w) taken &= ~((uint32_t)1 << (i & 31));
                }
            }
        }
    }
    for (uint32_t k = 256; k < ncf; ++k) {
        const uint32_t i = conf_rows[k];
        const uint64_t nf = sinfo[(size_t)b * PREFIX + i];
        const uint32_t cnt = (uint32_t)(nf >> 60);
        bool dropped = false;
        if (cnt == 6) {
            const uint32_t* row = mbase + (size_t)i * 64;
            const int iw = i >> 5;
            for (int w = 0; w <= iw; ++w) {
                uint32_t bits = row[w];
                if (w == iw) bits &= (((uint32_t)1 << (i & 31)) - 1u);
                const uint32_t tk = __builtin_amdgcn_readlane(taken, w);
                if (bits & tk) { dropped = true; break; }
            }
        } else {
            uint64_t p = nf;
            for (uint32_t c = 0; c < cnt; ++c) {
                const uint32_t j = (uint32_t)(p & 0xFFFu);
                p >>= 12;
                const uint32_t tk = __builtin_amdgcn_readlane(taken, (int)(j >> 5));
                if ((tk >> (j & 31)) & 1u) dropped = true;
            }
        }
        if (dropped) {
            const int w = (int)(i >> 5);
            if (lane == w) taken &= ~((uint32_t)1 << (i & 31));
        }
    }

    const uint32_t tpc = (uint32_t)__popc(taken);
    uint32_t tpref = tpc;
    for (int d = 1; d < 64; d <<= 1) {
        const uint32_t v = __shfl_up(tpref, d);
        if (lane >= d) tpref += v;
    }
    const uint32_t total = __shfl(tpref, 63);
    uint32_t rank = tpref - tpc;
    uint32_t w = taken;
    while (w) {
        const int q = __ffs(w) - 1;
        w &= w - 1;
        if (rank < (uint32_t)NPROP)
            kept_idx[(size_t)b * NPROP + rank] = (uint32_t)(lane * 32 + q);
        ++rank;
    }
    if (lane == 0) meta[MT_KEPT + b] = min(total, (uint32_t)NPROP);
}

__global__ __launch_bounds__(1024) void k_finish(const float4* __restrict__ boxes,
        uint32_t* meta, uint32_t* kept_idx, float4* __restrict__ out) {
    const int b = blockIdx.x;
    const float4* bx = boxes + (size_t)b * K_PRE;
    __shared__ float4 kb[NPROP];
    __shared__ uint32_t sflag;
    uint32_t kept = meta[MT_KEPT + b];
    if (kept < NPROP) {
        for (uint32_t k = threadIdx.x; k < kept; k += 1024)
            kb[k] = bx[kept_idx[(size_t)b * NPROP + k]];
        __syncthreads();
        for (int i = PREFIX; i < K_PRE && kept < NPROP; ++i) {
            if (threadIdx.x == 0) sflag = 0;
            __syncthreads();
            const float4 c = bx[i];
            const float areaC = (c.z - c.x) * (c.w - c.y);
            bool sup = false;
            for (uint32_t k = threadIdx.x; k < kept; k += 1024) {
                const float4 a = kb[k];
                const float yy1 = fmaxf(c.x, a.x), xx1 = fmaxf(c.y, a.y);
                const float yy2 = fminf(c.z, a.z), xx2 = fminf(c.w, a.w);
                const float inter = fmaxf(yy2 - yy1, 0.0f) * fmaxf(xx2 - xx1, 0.0f);
                const float areaA = (a.z - a.x) * (a.w - a.y);
                const float uni = fmaxf(areaC + areaA - inter, 1e-8f);
                if (inter / uni > NMS_THR) { sup = true; break; }
            }
            if (sup) atomicOr(&sflag, 1u);
            __syncthreads();
            if (sflag == 0) {
                if (threadIdx.x == 0) {
                    kept_idx[(size_t)b * NPROP + kept] = (uint32_t)i;
                    kb[kept] = c;
                }
                ++kept;
            }
            __syncthreads();
        }
        if (threadIdx.x == 0) meta[MT_KEPT + b] = kept;
    }
    __syncthreads();
    for (uint32_t k = threadIdx.x; k < NPROP; k += 1024) {
        float4 v = make_float4(0.f, 0.f, 0.f, 0.f);
        if (k < kept) v = bx[kept_idx[(size_t)b * NPROP + k]];
        out[(size_t)b * NPROP + k] = v;
    }
}

extern "C" void kernel_launch(void* const* d_in, const int* in_sizes, int n_in,
                              void* d_out, int out_size, void* d_ws, size_t ws_size,
                              hipStream_t stream) {
    const float4* probs4 = (const float4*)d_in[0];
    const float4* bbox   = (const float4*)d_in[1];
    const float4* anch   = (const float4*)d_in[2];
    char* ws = (char*)d_ws;
    if (ws_size < (size_t)WS_NEED) return;
    uint32_t* hist1 = (uint32_t*)(ws + HIST1_OFF);
    uint32_t* hist2 = (uint32_t*)(ws + HIST2_OFF);
    uint32_t* meta  = (uint32_t*)(ws + META_OFF);
    uint64_t* cand  = (uint64_t*)(ws + CAND_OFF);
    float4*   boxes = (float4*)(ws + BOXES_OFF);
    uint32_t* mask  = (uint32_t*)(ws + MASK_OFF);
    uint32_t* kidx  = (uint32_t*)(ws + KIDX_OFF);
    uint64_t* candc = (uint64_t*)(ws + CANDC_OFF);
    uint64_t* sinfo = (uint64_t*)(ws + HIST1_OFF);   // reuse: hist1 dead after k_rankfd
    uint32_t* cbm   = (uint32_t*)(ws + HIST2_OFF);   // reuse: hist2 dead after k_rankfd
    uint32_t* ranks = (uint32_t*)(ws + MASK_OFF);    // reuse: consumed by k_decode before k_matrix writes

    k_zero<<<dim3((HZERO + 255) / 256), dim3(256), 0, stream>>>(hist1, meta);
    k_hist<<<dim3(512), dim3(256), 0, stream>>>(probs4, hist1);
    k_hist2c<<<dim3(2048), dim3(256), 0, stream>>>(probs4, hist1, meta, hist2, candc);
    k_rankfd<<<dim3(BATCH), dim3(1024), 0, stream>>>(hist1, hist2, meta, candc, cand, ranks);
    k_decode<<<dim3(BATCH * 32), dim3(256), 0, stream>>>(cand, meta, ranks, bbox, anch, boxes);
    k_matrix<<<dim3(BATCH * NTILT), dim3(256), 0, stream>>>(boxes, mask);
    k_conflict<<<dim3(BATCH * 8), dim3(256), 0, stream>>>(mask, sinfo, cbm);
    k_greedy<<<dim3(BATCH), dim3(64), 0, stream>>>(mask, sinfo, cbm, meta, kidx);
    k_finish<<<dim3(BATCH), dim3(1024), 0, stream>>>(boxes, meta, kidx, (float4*)d_out);
}

// Round 20
// 79.332 us; speedup vs baseline: 1.9930x; 1.3815x over previous
//
#include <hip/hip_runtime.h>
#include <stdint.h>

#define BATCH 8
#define NN 262144
#define K_PRE 6000
#define NPROP 1000
#define NMS_THR 0.7f
#define CAND_CAP 8192
#define CANDC_CAP 16384
#define PREFIX 2048
#define NB1 16384
#define NB2 4096
#define NBF 8192        // fine bins above TFIX, 64-key granularity
#define RBINS 4096
#define NTILT 528       // lower-triangle tiles: 32*33/2
#define TFIX 0xBF780000u  // fkey(0.96875); expected ~8192 of 262144 above; %64==0

// meta u32 indices
#define MT_T2 0        // [0..7]   final threshold
#define MT_KEPT 16     // [16..23] kept count
#define MT_T1 24       // [24..31] coarse bucket (fallback)
#define MT_CUM 32      // [32..39] cum above coarse bucket (fallback)
#define MT_OVF 40      // [40..47] per-block stash overflow flag
#define MT_CNT(b)   (64 + 32*(b))       // exact candidate count
#define MT_CNTC(b)  (64 + 32*(b) + 16)  // fast-path stash count
#define MT_CNTC2(b) (64 + 32*(b) + 20)  // fallback stash count

// workspace layout (bytes)
#define HIST1_OFF 0                                   // BATCH*NB1*4 = 524288 (fallback)
#define HIST2_OFF (HIST1_OFF + BATCH*NB1*4)           // BATCH*NB2*4 = 131072 (fallback)
#define META_OFF  (HIST2_OFF + BATCH*NB2*4)           // 2048 B
#define CAND_OFF  (META_OFF + 2048)
#define BOXES_OFF (CAND_OFF + BATCH*CAND_CAP*8)       // BATCH*K_PRE*16
#define MASK_OFF  (BOXES_OFF + BATCH*K_PRE*16)        // BATCH*PREFIX*64*4 = 4 MB
#define KIDX_OFF  (MASK_OFF + (size_t)BATCH*PREFIX*64*4)
#define CANDC_OFF (KIDX_OFF + BATCH*NPROP*4)          // BATCH*CANDC_CAP*8 = 1 MB
#define FHIST_OFF (CANDC_OFF + (size_t)BATCH*CANDC_CAP*8)  // BATCH*NBF*4 = 256KB
#define WS_NEED   (FHIST_OFF + (size_t)BATCH*NBF*4)

// region reuse (all deps stream-ordered):
//  - ranks -> MASK region (written by k_rankfd, read by k_decode, then k_matrix overwrites)
//  - sinfo -> HIST1 region (dead after k_rankfd)
//  - cbm   -> HIST2 region (dead after k_rankfd)

#define HZERO_H (BATCH * (NB1 + NB2))                 // u32s: hist1+hist2 (contiguous)
#define HZERO_F (BATCH * NBF)                         // u32s: fhist (separate region!)

__device__ __forceinline__ uint32_t fkey(float f) {
    uint32_t b = __float_as_uint(f);
    return b ^ (uint32_t)(((int32_t)b >> 31) | 0x80000000u);
}

__device__ __forceinline__ bool path_valid(const uint32_t* meta, int b) {
    const uint32_t c = meta[MT_CNTC(b)];
    return c >= (uint32_t)K_PRE && c <= (uint32_t)CANDC_CAP && meta[MT_OVF + b] == 0;
}

// R19 bug fixed: fhist is NOT contiguous with hist1/hist2 -- zero it via its
// own pointer; never touch bytes outside the three histogram regions.
__global__ void k_zero(uint32_t* h, uint32_t* fh, uint32_t* meta) {
    const int i = blockIdx.x * 256 + threadIdx.x;
    if (i < HZERO_H) h[i] = 0;
    else if (i < HZERO_H + HZERO_F) fh[i - HZERO_H] = 0;
    if (blockIdx.x == 0 && threadIdx.x < BATCH) {
        meta[MT_CNTC(threadIdx.x)] = 0;
        meta[MT_CNTC2(threadIdx.x)] = 0;
        meta[MT_OVF + threadIdx.x] = 0;
    }
}

// THE single probs pass (2048 blocks = 256/batch, 1024 scores each):
// u >= TFIX -> global atomic into 8192-bin fine hist (~1 hit/bin) + LDS stash
// (expected 32/block, cap 1024; overflow -> OVF -> exact fallback path).
__global__ __launch_bounds__(256) void k_histf(const float4* __restrict__ probs4,
        uint32_t* __restrict__ fhist, uint32_t* cnt_meta, uint64_t* __restrict__ cand_c) {
    __shared__ uint64_t stash[1024];
    __shared__ uint32_t lcnt, lbase;
    const int b = blockIdx.x >> 8;
    const int s = blockIdx.x & 255;
    if (threadIdx.x == 0) lcnt = 0;
    __syncthreads();
    const float4* p = probs4 + (size_t)b * (NN / 2) + (size_t)s * 512;
    uint32_t* fh = fhist + (size_t)b * NBF;
    const uint32_t base_n = (uint32_t)s * 1024;
    for (int i = threadIdx.x; i < 512; i += 256) {
        const float4 v = p[i];
        const uint32_t u1 = fkey(v.y);
        const uint32_t u2 = fkey(v.w);
        if (u1 >= TFIX) {
            uint32_t bin = (u1 - TFIX) >> 6; if (bin > NBF - 1) bin = NBF - 1;
            atomicAdd(&fh[bin], 1u);
            const uint32_t pos = atomicAdd(&lcnt, 1u);
            if (pos < 1024) stash[pos] = ((uint64_t)u1 << 32) | (uint32_t)(~(base_n + 2u * (uint32_t)i));
        }
        if (u2 >= TFIX) {
            uint32_t bin = (u2 - TFIX) >> 6; if (bin > NBF - 1) bin = NBF - 1;
            atomicAdd(&fh[bin], 1u);
            const uint32_t pos = atomicAdd(&lcnt, 1u);
            if (pos < 1024) stash[pos] = ((uint64_t)u2 << 32) | (uint32_t)(~(base_n + 2u * (uint32_t)i + 1u));
        }
    }
    __syncthreads();
    if (threadIdx.x == 0) {
        if (lcnt > 1024) atomicOr(&cnt_meta[MT_OVF + b], 1u);
        lbase = atomicAdd(&cnt_meta[MT_CNTC(b)], min(lcnt, 1024u));
    }
    __syncthreads();
    uint64_t* cc = cand_c + (size_t)b * CANDC_CAP;
    const uint32_t n_loc = min(lcnt, 1024u), base = lbase;
    for (uint32_t i = threadIdx.x; i < n_loc; i += 256) {
        const uint32_t pos = base + i;
        if (pos < CANDC_CAP) cc[pos] = stash[i];
    }
}

// ---- gated fallback chain (no-ops when fast path valid) ----
__global__ __launch_bounds__(256) void k_hist_fb(const float4* __restrict__ probs4,
        const uint32_t* __restrict__ meta, uint32_t* __restrict__ hist) {
    const int b = blockIdx.x >> 6;
    if (path_valid(meta, b)) return;
    __shared__ uint32_t h[NB1];
    for (int i = threadIdx.x; i < NB1; i += 256) h[i] = 0;
    __syncthreads();
    const int s = blockIdx.x & 63;
    const float4* p = probs4 + (size_t)b * (NN / 2) + (size_t)s * 2048;
    for (int i = threadIdx.x; i < 2048; i += 256) {
        const float4 v = p[i];
        atomicAdd(&h[fkey(v.y) >> 18], 1u);
        atomicAdd(&h[fkey(v.w) >> 18], 1u);
    }
    __syncthreads();
    uint32_t* gh = hist + (size_t)b * NB1;
    for (int i = threadIdx.x; i < NB1; i += 256)
        if (h[i]) atomicAdd(&gh[i], h[i]);
}

__global__ __launch_bounds__(256) void k_select_fb(const uint32_t* __restrict__ hist,
                                                   uint32_t* meta) {
    const int b = blockIdx.x;
    if (path_valid(meta, b)) return;
    const uint32_t* gh = hist + (size_t)b * NB1;
    __shared__ uint32_t part[256];
    const int t = threadIdx.x;
    uint32_t s = 0;
    const int hi = NB1 - 64 * t;
    for (int i = hi - 64; i < hi; ++i) s += gh[i];
    part[t] = s;
    __syncthreads();
    if (t == 0) {
        uint32_t cum = 0;
        int strip = 0;
        for (; strip < 256; ++strip) {
            if (cum + part[strip] >= (uint32_t)K_PRE) break;
            cum += part[strip];
        }
        int t1 = 0;
        if (strip < 256) {
            const int top = NB1 - 64 * strip;
            int i = top - 1;
            for (; i >= top - 64; --i) {
                const uint32_t c = gh[i];
                if (cum + c >= (uint32_t)K_PRE) break;
                cum += c;
            }
            if (i < top - 64) i = top - 64;
            t1 = i;
        }
        meta[MT_T1 + b] = (uint32_t)t1;
        meta[MT_CUM + b] = cum;
    }
}

__global__ __launch_bounds__(256) void k_compact_fb(const float4* __restrict__ probs4,
        uint32_t* meta, uint32_t* __restrict__ hist2, uint64_t* __restrict__ cand_c) {
    const int b = blockIdx.x >> 8;
    if (path_valid(meta, b)) return;
    __shared__ uint64_t stash[1024];
    __shared__ uint32_t lcnt, lbase;
    const int s = blockIdx.x & 255;
    const uint32_t t1 = meta[MT_T1 + b];
    const uint32_t Tc = t1 << 18;
    if (threadIdx.x == 0) lcnt = 0;
    __syncthreads();
    const float4* p = probs4 + (size_t)b * (NN / 2) + (size_t)s * 512;
    uint32_t* gh = hist2 + (size_t)b * NB2;
    const uint32_t base_n = (uint32_t)s * 1024;
    for (int i = threadIdx.x; i < 512; i += 256) {
        const float4 v = p[i];
        const uint32_t u1 = fkey(v.y);
        const uint32_t u2 = fkey(v.w);
        if ((u1 >> 18) == t1) atomicAdd(&gh[(u1 >> 6) & 0xFFFu], 1u);
        if ((u2 >> 18) == t1) atomicAdd(&gh[(u2 >> 6) & 0xFFFu], 1u);
        if (u1 >= Tc) {
            const uint32_t pos = atomicAdd(&lcnt, 1u);
            stash[pos] = ((uint64_t)u1 << 32) | (uint32_t)(~(base_n + 2u * (uint32_t)i));
        }
        if (u2 >= Tc) {
            const uint32_t pos = atomicAdd(&lcnt, 1u);
            stash[pos] = ((uint64_t)u2 << 32) | (uint32_t)(~(base_n + 2u * (uint32_t)i + 1u));
        }
    }
    __syncthreads();
    if (threadIdx.x == 0) lbase = atomicAdd(&meta[MT_CNTC2(b)], lcnt);
    __syncthreads();
    uint64_t* cc = cand_c + (size_t)b * CANDC_CAP;
    const uint32_t n_loc = lcnt, base = lbase;
    for (uint32_t i = threadIdx.x; i < n_loc; i += 256) {
        const uint32_t pos = base + i;
        if (pos < CANDC_CAP) cc[pos] = stash[i];
    }
}

// Fused: T2 selection (fine-hist suffix when valid; hist1+hist2 fallback) +
// stash filter + compacted cand write + binning ranks. One block per batch.
__global__ __launch_bounds__(1024) void k_rankfd(const uint32_t* __restrict__ fhist,
        const uint32_t* __restrict__ hist1, const uint32_t* __restrict__ hist2,
        uint32_t* meta, const uint64_t* __restrict__ cand_c, uint64_t* __restrict__ cand,
        uint32_t* __restrict__ ranks) {
    __shared__ uint64_t skey[CAND_CAP];     // 64 KB
    __shared__ uint16_t sbin[CAND_CAP];     // 16 KB
    __shared__ uint32_t cnt[RBINS];         // 16 KB
    __shared__ uint32_t S[RBINS];           // 16 KB
    __shared__ uint16_t order[CAND_CAP];    // 16 KB
    __shared__ uint32_t sc[1024];           // 4 KB
    __shared__ uint32_t part[256], orig[256];
    __shared__ uint32_t l_strip, l_cumb, l_t1, l_cum, l_T2, l_m;
    const int b = blockIdx.x;
    const int t = threadIdx.x;
    const bool valid = path_valid(meta, b);

    if (valid) {
        // suffix scan over 1024 strips of 8 fine bins (ascending key layout)
        const uint32_t* fh = fhist + (size_t)b * NBF;
        uint32_t ssum = 0;
#pragma unroll
        for (int k = 0; k < 8; ++k) ssum += fh[8 * t + k];
        sc[t] = ssum;
        __syncthreads();
        for (int d = 1; d < 1024; d <<= 1) {
            const uint32_t v = (t + d < 1024) ? sc[t + d] : 0;
            __syncthreads();
            sc[t] += v;
            __syncthreads();
        }
        if (sc[t] >= (uint32_t)K_PRE && (t == 1023 || sc[t + 1] < (uint32_t)K_PRE))
            l_strip = (uint32_t)t;
        __syncthreads();
        if (t == 0) {
            const uint32_t ts = l_strip;
            uint32_t run = (ts < 1023) ? sc[ts + 1] : 0;
            int bin = 8 * (int)ts + 7;
            for (; bin >= 8 * (int)ts; --bin) {
                run += fh[bin];
                if (run >= (uint32_t)K_PRE) break;
            }
            l_T2 = TFIX + ((uint32_t)bin << 6);   // same 64-key lattice as fallback T2
            l_m = 0;
        }
        __syncthreads();
    } else {
        // ---- fallback phase 1: t1 & cum from hist1 ----
        const uint32_t* gh1 = hist1 + (size_t)b * NB1;
        const uint32_t* gh2 = hist2 + (size_t)b * NB2;
        if (t < 256) {
            uint32_t sum = 0;
            const int hi = NB1 - 64 * t;
            for (int i = hi - 64; i < hi; ++i) sum += gh1[i];
            orig[t] = sum; part[t] = sum;
        }
        __syncthreads();
        for (int d = 1; d < 256; d <<= 1) {
            uint32_t v = 0;
            if (t < 256 && t >= d) v = part[t - d];
            __syncthreads();
            if (t < 256) part[t] += v;
            __syncthreads();
        }
        if (t < 256) {
            const uint32_t incl = part[t], cumb = incl - orig[t];
            if (incl >= (uint32_t)K_PRE && cumb < (uint32_t)K_PRE) { l_strip = t; l_cumb = cumb; }
        }
        __syncthreads();
        if (t < 64) {
            const int top = NB1 - 64 * (int)l_strip;
            const uint32_t c = gh1[top - 1 - t];
            uint32_t p = c;
            for (int d = 1; d < 64; d <<= 1) {
                const uint32_t v = __shfl_up(p, d);
                if (t >= d) p += v;
            }
            const uint32_t tot = l_cumb + p;
            if (tot >= (uint32_t)K_PRE && tot - c < (uint32_t)K_PRE) {
                l_t1 = (uint32_t)(top - 1 - t);
                l_cum = tot - c;
            }
        }
        __syncthreads();
        const uint32_t t1 = l_t1, cum = l_cum;
        // ---- fallback phase 2: T2 from hist2, offset by cum ----
        if (t < 256) {
            uint32_t sum = 0;
            const int hi = NB2 - 16 * t;
            for (int i = hi - 16; i < hi; ++i) sum += gh2[i];
            orig[t] = sum; part[t] = sum;
        }
        __syncthreads();
        for (int d = 1; d < 256; d <<= 1) {
            uint32_t v = 0;
            if (t < 256 && t >= d) v = part[t - d];
            __syncthreads();
            if (t < 256) part[t] += v;
            __syncthreads();
        }
        if (t < 256) {
            const uint32_t incl = cum + part[t], cumb = incl - orig[t];
            if (incl >= (uint32_t)K_PRE && cumb < (uint32_t)K_PRE) { l_strip = t; l_cumb = cumb; }
        }
        __syncthreads();
        if (t < 16) {
            const int top = NB2 - 16 * (int)l_strip;
            const uint32_t c = gh2[top - 1 - t];
            uint32_t p = c;
            for (int d = 1; d < 16; d <<= 1) {
                const uint32_t v = __shfl_up(p, d);
                if (t >= d) p += v;
            }
            const uint32_t tot = l_cumb + p;
            if (tot >= (uint32_t)K_PRE && tot - c < (uint32_t)K_PRE)
                l_T2 = (t1 << 18) | ((uint32_t)(top - 1 - t) << 6);
        }
        if (t == 0) l_m = 0;
        __syncthreads();
    }
    const uint32_t T2 = l_T2;

    // ---- filter stash by exact T2 into LDS ----
    const uint32_t mc = min(valid ? meta[MT_CNTC(b)] : meta[MT_CNTC2(b)], (uint32_t)CANDC_CAP);
    const uint64_t* cc = cand_c + (size_t)b * CANDC_CAP;
    for (uint32_t i = (uint32_t)t; i < mc; i += 1024) {
        const uint64_t k = cc[i];
        if ((uint32_t)(k >> 32) >= T2) {
            const uint32_t pos = atomicAdd(&l_m, 1u);
            if (pos < CAND_CAP) skey[pos] = k;
        }
    }
    __syncthreads();
    const uint32_t m = min(l_m, (uint32_t)CAND_CAP);
    if (t == 0) { meta[MT_CNT(b)] = m; meta[MT_T2 + b] = T2; }
    uint64_t* cb = cand + (size_t)b * CAND_CAP;
    for (uint32_t i = (uint32_t)t; i < m; i += 1024) cb[i] = skey[i];

    // ---- binning + suffix scan + within-bin exact rank ----
    const uint32_t R = 0xBF800000u - T2;
    const int w = 32 - __clz(R | 1);
    const int sh = (w > 12) ? (w - 12) : 0;
    for (int i = t; i < RBINS; i += 1024) cnt[i] = 0;
    __syncthreads();
    for (uint32_t i = (uint32_t)t; i < m; i += 1024) {
        uint32_t bin = (((uint32_t)(skey[i] >> 32)) - T2) >> sh;
        if (bin >= RBINS) bin = RBINS - 1;
        sbin[i] = (uint16_t)bin;
        atomicAdd(&cnt[bin], 1u);
    }
    __syncthreads();
    const uint32_t c1 = cnt[4 * t + 1], c2 = cnt[4 * t + 2], c3 = cnt[4 * t + 3];
    sc[t] = cnt[4 * t] + c1 + c2 + c3;
    __syncthreads();
    for (int d = 1; d < 1024; d <<= 1) {
        const uint32_t v = (t + d < 1024) ? sc[t + d] : 0;
        __syncthreads();
        sc[t] += v;
        __syncthreads();
    }
    const uint32_t Spart = (t + 1 < 1024) ? sc[t + 1] : 0;
    S[4 * t + 3] = Spart;
    S[4 * t + 2] = Spart + c3;
    S[4 * t + 1] = Spart + c3 + c2;
    S[4 * t + 0] = Spart + c3 + c2 + c1;
    __syncthreads();
    for (uint32_t i = (uint32_t)t; i < m; i += 1024) {
        const uint32_t bin = sbin[i];
        const uint32_t intra = atomicSub(&cnt[bin], 1u) - 1u;
        order[S[bin] + intra] = (uint16_t)i;
    }
    __syncthreads();
    uint32_t* rb = ranks + (size_t)b * CAND_CAP;
    for (uint32_t i = (uint32_t)t; i < m; i += 1024) {
        const uint32_t bin = sbin[i];
        const uint64_t ki = skey[i];
        const uint32_t start = S[bin];
        const uint32_t end = (bin > 0) ? S[bin - 1] : m;
        uint32_t rank = start;
        for (uint32_t s2 = start; s2 < end; ++s2)
            if (skey[order[s2]] > ki) ++rank;
        rb[i] = rank;
    }
}

// Decode gather with full parallelism (256 blocks).
__global__ __launch_bounds__(256) void k_decode(const uint64_t* __restrict__ cand,
        const uint32_t* __restrict__ meta, const uint32_t* __restrict__ ranks,
        const float4* __restrict__ bbox, const float4* __restrict__ anch,
        float4* __restrict__ boxes) {
    const int b = blockIdx.x >> 5;
    const int i = ((blockIdx.x & 31) << 8) + threadIdx.x;
    const uint32_t m = min(meta[MT_CNT(b)], (uint32_t)CAND_CAP);
    if ((uint32_t)i >= m) return;
    const uint32_t rank = ranks[(size_t)b * CAND_CAP + i];
    if (rank >= (uint32_t)K_PRE) return;
    const uint64_t ki = cand[(size_t)b * CAND_CAP + i];
    const uint32_t n = ~((uint32_t)ki);
    const float4 a = anch[(size_t)b * NN + n];
    const float4 d = bbox[(size_t)b * NN + n];
    float h = a.z - a.x, w = a.w - a.y;
    const float cy0 = a.x + 0.5f * h + d.x * 0.1f * h;
    const float cx0 = a.y + 0.5f * w + d.y * 0.1f * w;
    h = h * expf(d.z * 0.2f);
    w = w * expf(d.w * 0.2f);
    float4 o;
    o.x = fminf(fmaxf(cy0 - 0.5f * h, 0.0f), 1.0f);
    o.y = fminf(fmaxf(cx0 - 0.5f * w, 0.0f), 1.0f);
    o.z = fminf(fmaxf(cy0 + 0.5f * h, 0.0f), 1.0f);
    o.w = fminf(fmaxf(cx0 + 0.5f * w, 0.0f), 1.0f);
    boxes[(size_t)b * K_PRE + rank] = o;
}

// IoU bit-matrix, LOWER TRIANGLE tiles only (tj <= ti).
__global__ __launch_bounds__(256) void k_matrix(const float4* __restrict__ boxes,
                                                uint32_t* __restrict__ mask) {
    const int b = blockIdx.x / NTILT;
    const int idx = blockIdx.x - b * NTILT;
    int ti = (int)((sqrtf(8.0f * (float)idx + 1.0f) - 1.0f) * 0.5f);
    while ((ti + 1) * (ti + 2) / 2 <= idx) ++ti;
    while (ti * (ti + 1) / 2 > idx) --ti;
    const int tj = idx - ti * (ti + 1) / 2;
    __shared__ float4 rb[64], cb[64];
    __shared__ uint32_t wbits[128];
    const float4* bx = boxes + (size_t)b * K_PRE;
    const int t = threadIdx.x;
    if (t < 64) rb[t] = bx[ti * 64 + t];
    else if (t < 128) cb[t - 64] = bx[tj * 64 + (t - 64)];
    if (t < 128) wbits[t] = 0;
    __syncthreads();
    const int r = t >> 2;
    const int cq = t & 3;
    const float4 a = rb[r];
    const float areaA = (a.z - a.x) * (a.w - a.y);
    uint32_t bits = 0;
#pragma unroll
    for (int jj = 0; jj < 16; ++jj) {
        const float4 cc = cb[cq * 16 + jj];
        const float yy1 = fmaxf(a.x, cc.x), xx1 = fmaxf(a.y, cc.y);
        const float yy2 = fminf(a.z, cc.z), xx2 = fminf(a.w, cc.w);
        const float inter = fmaxf(yy2 - yy1, 0.0f) * fmaxf(xx2 - xx1, 0.0f);
        const float areaC = (cc.z - cc.x) * (cc.w - cc.y);
        const float uni = fmaxf(areaA + areaC - inter, 1e-8f);
        if (inter / uni > NMS_THR) bits |= (1u << jj);
    }
    atomicOr(&wbits[r * 2 + (cq >> 1)], bits << ((cq & 1) * 16));
    __syncthreads();
    if (t < 128) {
        const int rr = t >> 1, ww = t & 1;
        mask[((size_t)b * PREFIX + ti * 64 + rr) * 64 + tj * 2 + ww] = wbits[rr * 2 + ww];
    }
}

// Conflict extraction (lower triangle only; words > iw masked).
__global__ __launch_bounds__(256) void k_conflict(const uint32_t* __restrict__ mask,
        uint64_t* __restrict__ sinfo, uint32_t* __restrict__ cbm) {
    const int b = blockIdx.x >> 3;
    const int s = blockIdx.x & 7;
    const int i = (s << 8) + threadIdx.x;
    const uint4* row4 = (const uint4*)(mask + ((size_t)b * PREFIX + i) * 64);
    const int iw = i >> 5;
    const uint32_t tailmask = ((uint32_t)1 << (i & 31)) - 1u;
    uint32_t cnt = 0;
    uint64_t packed = 0;
    for (int c = 0; c <= (iw >> 2); ++c) {
        const uint4 q = row4[c];
        uint32_t ws[4] = {q.x, q.y, q.z, q.w};
#pragma unroll
        for (int k = 0; k < 4; ++k) {
            const int w = c * 4 + k;
            uint32_t bits = ws[k];
            if (w > iw) bits = 0;
            else if (w == iw) bits &= tailmask;
            while (bits) {
                const int bp = __ffs(bits) - 1;
                bits &= bits - 1;
                if (cnt < 5) packed |= (uint64_t)(uint32_t)(w * 32 + bp) << (12 * cnt);
                ++cnt;
            }
        }
    }
    packed |= (uint64_t)(cnt <= 5 ? cnt : 6) << 60;   // 6 = heavy (rescan row)
    sinfo[(size_t)b * PREFIX + i] = packed;
    const unsigned long long bm = __ballot(cnt != 0);
    const int wv = threadIdx.x >> 6;
    const int lid = threadIdx.x & 63;
    if (lid == 0) cbm[(size_t)b * 64 + (s << 3) + wv * 2] = (uint32_t)bm;
    else if (lid == 1) cbm[(size_t)b * 64 + (s << 3) + wv * 2 + 1] = (uint32_t)(bm >> 32);
}

// Greedy resolution: taken-bitmap in lane registers; only conflicted rows
// (~3%) resolved serially ascending; emit first min(1000,total) taken rows.
__global__ __launch_bounds__(64) void k_greedy(const uint32_t* __restrict__ mask,
        const uint64_t* __restrict__ sinfo, const uint32_t* __restrict__ cbm,
        uint32_t* meta, uint32_t* __restrict__ kept_idx) {
    __shared__ uint32_t conf_rows[PREFIX];
    __shared__ uint32_t ncf_s;
    const int b = blockIdx.x;
    const int lane = threadIdx.x;
    const uint32_t cw = cbm[(size_t)b * 64 + lane];
    uint32_t taken = 0xFFFFFFFFu;

    const uint32_t pc = (uint32_t)__popc(cw);
    uint32_t pref = pc;
    for (int d = 1; d < 64; d <<= 1) {
        const uint32_t v = __shfl_up(pref, d);
        if (lane >= d) pref += v;
    }
    const uint32_t ncf = __shfl(pref, 63);
    uint32_t idx = pref - pc;
    uint32_t tm = cw;
    while (tm) {
        const int q = __ffs(tm) - 1;
        tm &= tm - 1;
        conf_rows[idx] = (uint32_t)(lane * 32 + q);
        ++idx;
    }
    if (lane == 0) ncf_s = ncf;
    __syncthreads();

    uint32_t r_i[4], r_lo[4], r_hi[4];
#pragma unroll
    for (int r = 0; r < 4; ++r) {
        const uint32_t k = (uint32_t)(r * 64 + lane);
        const uint32_t ri = (k < ncf) ? conf_rows[k] : 0;
        const uint64_t nf = (k < ncf) ? sinfo[(size_t)b * PREFIX + ri] : 0ull;
        r_i[r] = ri;
        r_lo[r] = (uint32_t)nf;
        r_hi[r] = (uint32_t)(nf >> 32);
    }

    const uint32_t* mbase = mask + (size_t)b * PREFIX * 64;

#pragma unroll
    for (int seg = 0; seg < 4; ++seg) {
        const uint32_t segbase = (uint32_t)(seg * 64);
        if (segbase < ncf) {
            const uint32_t segcnt = min(64u, ncf - segbase);
            for (uint32_t k2 = 0; k2 < segcnt; ++k2) {
                const uint32_t i  = __builtin_amdgcn_readlane(r_i[seg], (int)k2);
                const uint32_t lo = __builtin_amdgcn_readlane(r_lo[seg], (int)k2);
                const uint32_t hi = __builtin_amdgcn_readlane(r_hi[seg], (int)k2);
                const uint32_t cnt = hi >> 28;
                bool dropped = false;
                if (cnt == 6) {
                    const uint32_t* row = mbase + (size_t)i * 64;
                    const int iw = i >> 5;
                    for (int w = 0; w <= iw; ++w) {
                        uint32_t bits = row[w];
                        if (w == iw) bits &= (((uint32_t)1 << (i & 31)) - 1u);
                        const uint32_t tk = __builtin_amdgcn_readlane(taken, w);
                        if (bits & tk) { dropped = true; break; }
                    }
                } else {
                    uint64_t p = ((uint64_t)hi << 32) | lo;
                    for (uint32_t c = 0; c < cnt; ++c) {
                        const uint32_t j = (uint32_t)(p & 0xFFFu);
                        p >>= 12;
                        const uint32_t tk = __builtin_amdgcn_readlane(taken, (int)(j >> 5));
                        if ((tk >> (j & 31)) & 1u) dropped = true;
                    }
                }
                if (dropped) {
                    const int w = (int)(i >> 5);
                    if (lane == w) taken &= ~((uint32_t)1 << (i & 31));
                }
            }
        }
    }
    for (uint32_t k = 256; k < ncf; ++k) {
        const uint32_t i = conf_rows[k];
        const uint64_t nf = sinfo[(size_t)b * PREFIX + i];
        const uint32_t cnt = (uint32_t)(nf >> 60);
        bool dropped = false;
        if (cnt == 6) {
            const uint32_t* row = mbase + (size_t)i * 64;
            const int iw = i >> 5;
            for (int w = 0; w <= iw; ++w) {
                uint32_t bits = row[w];
                if (w == iw) bits &= (((uint32_t)1 << (i & 31)) - 1u);
                const uint32_t tk = __builtin_amdgcn_readlane(taken, w);
                if (bits & tk) { dropped = true; break; }
            }
        } else {
            uint64_t p = nf;
            for (uint32_t c = 0; c < cnt; ++c) {
                const uint32_t j = (uint32_t)(p & 0xFFFu);
                p >>= 12;
                const uint32_t tk = __builtin_amdgcn_readlane(taken, (int)(j >> 5));
                if ((tk >> (j & 31)) & 1u) dropped = true;
            }
        }
        if (dropped) {
            const int w = (int)(i >> 5);
            if (lane == w) taken &= ~((uint32_t)1 << (i & 31));
        }
    }

    const uint32_t tpc = (uint32_t)__popc(taken);
    uint32_t tpref = tpc;
    for (int d = 1; d < 64; d <<= 1) {
        const uint32_t v = __shfl_up(tpref, d);
        if (lane >= d) tpref += v;
    }
    const uint32_t total = __shfl(tpref, 63);
    uint32_t rank = tpref - tpc;
    uint32_t w = taken;
    while (w) {
        const int q = __ffs(w) - 1;
        w &= w - 1;
        if (rank < (uint32_t)NPROP)
            kept_idx[(size_t)b * NPROP + rank] = (uint32_t)(lane * 32 + q);
        ++rank;
    }
    if (lane == 0) meta[MT_KEPT + b] = min(total, (uint32_t)NPROP);
}

__global__ __launch_bounds__(1024) void k_finish(const float4* __restrict__ boxes,
        uint32_t* meta, uint32_t* kept_idx, float4* __restrict__ out) {
    const int b = blockIdx.x;
    const float4* bx = boxes + (size_t)b * K_PRE;
    __shared__ float4 kb[NPROP];
    __shared__ uint32_t sflag;
    uint32_t kept = meta[MT_KEPT + b];
    if (kept < NPROP) {
        for (uint32_t k = threadIdx.x; k < kept; k += 1024)
            kb[k] = bx[kept_idx[(size_t)b * NPROP + k]];
        __syncthreads();
        for (int i = PREFIX; i < K_PRE && kept < NPROP; ++i) {
            if (threadIdx.x == 0) sflag = 0;
            __syncthreads();
            const float4 c = bx[i];
            const float areaC = (c.z - c.x) * (c.w - c.y);
            bool sup = false;
            for (uint32_t k = threadIdx.x; k < kept; k += 1024) {
                const float4 a = kb[k];
                const float yy1 = fmaxf(c.x, a.x), xx1 = fmaxf(c.y, a.y);
                const float yy2 = fminf(c.z, a.z), xx2 = fminf(c.w, a.w);
                const float inter = fmaxf(yy2 - yy1, 0.0f) * fmaxf(xx2 - xx1, 0.0f);
                const float areaA = (a.z - a.x) * (a.w - a.y);
                const float uni = fmaxf(areaC + areaA - inter, 1e-8f);
                if (inter / uni > NMS_THR) { sup = true; break; }
            }
            if (sup) atomicOr(&sflag, 1u);
            __syncthreads();
            if (sflag == 0) {
                if (threadIdx.x == 0) {
                    kept_idx[(size_t)b * NPROP + kept] = (uint32_t)i;
                    kb[kept] = c;
                }
                ++kept;
            }
            __syncthreads();
        }
        if (threadIdx.x == 0) meta[MT_KEPT + b] = kept;
    }
    __syncthreads();
    for (uint32_t k = threadIdx.x; k < NPROP; k += 1024) {
        float4 v = make_float4(0.f, 0.f, 0.f, 0.f);
        if (k < kept) v = bx[kept_idx[(size_t)b * NPROP + k]];
        out[(size_t)b * NPROP + k] = v;
    }
}

extern "C" void kernel_launch(void* const* d_in, const int* in_sizes, int n_in,
                              void* d_out, int out_size, void* d_ws, size_t ws_size,
                              hipStream_t stream) {
    const float4* probs4 = (const float4*)d_in[0];
    const float4* bbox   = (const float4*)d_in[1];
    const float4* anch   = (const float4*)d_in[2];
    char* ws = (char*)d_ws;
    if (ws_size < (size_t)WS_NEED) return;
    uint32_t* hist1 = (uint32_t*)(ws + HIST1_OFF);
    uint32_t* hist2 = (uint32_t*)(ws + HIST2_OFF);
    uint32_t* meta  = (uint32_t*)(ws + META_OFF);
    uint64_t* cand  = (uint64_t*)(ws + CAND_OFF);
    float4*   boxes = (float4*)(ws + BOXES_OFF);
    uint32_t* mask  = (uint32_t*)(ws + MASK_OFF);
    uint32_t* kidx  = (uint32_t*)(ws + KIDX_OFF);
    uint64_t* candc = (uint64_t*)(ws + CANDC_OFF);
    uint32_t* fhist = (uint32_t*)(ws + FHIST_OFF);
    uint64_t* sinfo = (uint64_t*)(ws + HIST1_OFF);   // reuse: hist1 dead after k_rankfd
    uint32_t* cbm   = (uint32_t*)(ws + HIST2_OFF);   // reuse: hist2 dead after k_rankfd
    uint32_t* ranks = (uint32_t*)(ws + MASK_OFF);    // reuse: consumed by k_decode before k_matrix writes

    k_zero<<<dim3((HZERO_H + HZERO_F + 255) / 256), dim3(256), 0, stream>>>(hist1, fhist, meta);
    k_histf<<<dim3(2048), dim3(256), 0, stream>>>(probs4, fhist, meta, candc);
    k_hist_fb<<<dim3(512), dim3(256), 0, stream>>>(probs4, meta, hist1);
    k_select_fb<<<dim3(BATCH), dim3(256), 0, stream>>>(hist1, meta);
    k_compact_fb<<<dim3(2048), dim3(256), 0, stream>>>(probs4, meta, hist2, candc);
    k_rankfd<<<dim3(BATCH), dim3(1024), 0, stream>>>(fhist, hist1, hist2, meta, candc, cand, ranks);
    k_decode<<<dim3(BATCH * 32), dim3(256), 0, stream>>>(cand, meta, ranks, bbox, anch, boxes);
    k_matrix<<<dim3(BATCH * NTILT), dim3(256), 0, stream>>>(boxes, mask);
    k_conflict<<<dim3(BATCH * 8), dim3(256), 0, stream>>>(mask, sinfo, cbm);
    k_greedy<<<dim3(BATCH), dim3(64), 0, stream>>>(mask, sinfo, cbm, meta, kidx);
    k_finish<<<dim3(BATCH), dim3(1024), 0, stream>>>(boxes, meta, kidx, (float4*)d_out);
}